// Round 6
// baseline (712.169 us; speedup 1.0000x reference)
//
#include <hip/hip_runtime.h>
#include <hip/hip_bf16.h>
#include <math.h>

#define DEVI __device__ __forceinline__

typedef __attribute__((ext_vector_type(4))) float f32x4;
typedef __attribute__((ext_vector_type(8))) short s16x8;
typedef __attribute__((ext_vector_type(4))) unsigned int u32x4;

DEVI float bf2f(ushort u){ union{unsigned int i; float f;} x; x.i = ((unsigned int)u)<<16; return x.f; }
DEVI ushort f2bf(float f){ union{float f; unsigned int i;} x; x.f = f;
  unsigned int r = x.i + 0x7fffu + ((x.i>>16)&1u); return (ushort)(r>>16); }

#define MFMA16(a,b,c) __builtin_amdgcn_mfma_f32_16x16x32_bf16(a,b,c,0,0,0)

// ---------------- fp32 -> bf16 convert, 4 elems/thread ----------------
__global__ __launch_bounds__(256) void cvt_bf16(const float* __restrict__ in, ushort* __restrict__ out){
  int i = blockIdx.x*256 + threadIdx.x;
  float4 v = ((const float4*)in)[i];
  ushort4 o; o.x = f2bf(v.x); o.y = f2bf(v.y); o.z = f2bf(v.z); o.w = f2bf(v.w);
  ((ushort4*)out)[i] = o;
}

DEVI void gl_lds16(const ushort* g, ushort* l){
  __builtin_amdgcn_global_load_lds((const __attribute__((address_space(1))) void*)g,
                                   (__attribute__((address_space(3))) void*)l, 16, 0, 0);
}

#define SBAR() __builtin_amdgcn_s_barrier()
#define LGKM0() do{ asm volatile("s_waitcnt lgkmcnt(0)" ::: "memory"); __builtin_amdgcn_sched_barrier(0); }while(0)
#define VMC8() asm volatile("s_waitcnt vmcnt(8)" ::: "memory")
#define VMC4() asm volatile("s_waitcnt vmcnt(4)" ::: "memory")

// ============ 256x256-tile GEMM, BK=32, triple-buffer, single read+MFMA region ============
// C[M,N] = A[M,K] * B[N,K]^T. 8 waves (2Mx4N). Per iter: stage K-tile t+2 (4 gl_lds),
// vmcnt(8) retires batch t, barrier, then {12 ds_read_b128 + 32 MFMA} in ONE region
// (waves skew -> LDS reads overlap MFMA issue), lgkm0, barrier. 2 barriers/iter.
// LDS [256][32] per operand; chunk swizzle blk = quad ^ ((row>>1)&3) (2-way, free),
// realized via pre-swizzled GLOBAL source col (linear gl_lds dest) + same XOR on read.
// XCD-region swizzle: XCD covers rpx tile-rows x cpx tile-cols, col-major walk.
template<int BF16_OUT>
__global__ __launch_bounds__(512, 2) void gemm256(const ushort* __restrict__ A,
                                                  const ushort* __restrict__ B,
                                                  void* __restrict__ Cv,
                                                  int M, int N, int K,
                                                  int rpx, int cpx){
  __shared__ ushort smem[49152];   // 3 bufs x {A[256][32], B[256][32]} = 96 KiB
  __shared__ ushort dummy[4096];
  const int tid = threadIdx.x, w = tid>>6, lane = tid&63;
  const int fr = lane&15, quad = lane>>4;
  const int wm = w>>2, wn = w&3;
  const int NT2 = K>>5;

  const int nbn = N>>8;
  const int bid = blockIdx.x;
  const int xcd = bid & 7, idx = bid >> 3;
  const int CGn = nbn / cpx;
  const int rgrp = xcd / CGn, cgrp = xcd % CGn;
  const int rloc = idx % rpx, cloc = idx / rpx;
  const long tileM = (long)(rgrp*rpx + rloc) << 8;
  const long tileN = (long)(cgrp*cpx + cloc) << 8;

  // staging: wave w covers rows w*16..w*16+15 (lo) / +128 (hi) of the 256-row tile.
  // linear LDS dest (lane*16B); global source col chunk pre-swizzled.
  const int srow = lane>>2;
  const int scol = ((lane&3) ^ ((lane>>3)&3))*8;
  const ushort* pSA = A + (tileM + w*16 + srow)*(long)K + scol;
  const ushort* pSB = B + (tileN + w*16 + srow)*(long)K + scol;
  const long h128 = 128l*K;
  const int dwv = w*512;                    // elems, wave-uniform LDS dest base
  ushort* dmy = dummy + dwv;

#define STG(bb,tt) do{ if((tt)<NT2){ const long kk=(long)(tt)<<5; \
    gl_lds16(pSA+kk,      smem+(bb)*16384+dwv); \
    gl_lds16(pSA+kk+h128, smem+(bb)*16384+4096+dwv); \
    gl_lds16(pSB+kk,      smem+(bb)*16384+8192+dwv); \
    gl_lds16(pSB+kk+h128, smem+(bb)*16384+12288+dwv); } \
    else { gl_lds16(pSA,dmy); gl_lds16(pSA,dmy); gl_lds16(pSB,dmy); gl_lds16(pSB,dmy);} }while(0)

  // read-side lane offsets (elems), same XOR as source permutation
  const int swz = (quad ^ ((fr>>1)&3))*8;
  const int laneA = (wm*128 + fr)*32 + swz;
  const int laneB = 8192 + (wn*64 + fr)*32 + swz;

  f32x4 acc[8][4];
  #pragma unroll
  for (int i=0;i<8;i++)
    #pragma unroll
    for (int j=0;j<4;j++) acc[i][j] = (f32x4){0.f,0.f,0.f,0.f};

  STG(0,0); STG(1,1);                       // 8 loads in flight

  for (int t=0; t<NT2; ++t){
    const int rb = t%3, sb = (t+2)%3;
    STG(sb, t+2);                           // 4 more; <=12 in flight
    VMC8();                                 // retire batch t (oldest 4)
    SBAR();
    const ushort* BR = smem + rb*16384;
    s16x8 af[8], bf[4];
    #pragma unroll
    for (int mt=0;mt<8;mt++) af[mt] = *(const s16x8*)(BR + laneA + mt*512);
    #pragma unroll
    for (int nt=0;nt<4;nt++) bf[nt] = *(const s16x8*)(BR + laneB + nt*512);
    __builtin_amdgcn_s_setprio(1);
    #pragma unroll
    for (int mt=0;mt<8;mt++)
      #pragma unroll
      for (int nt=0;nt<4;nt++)
        acc[mt][nt] = MFMA16(af[mt], bf[nt], acc[mt][nt]);
    __builtin_amdgcn_s_setprio(0);
    LGKM0();
    SBAR();
  }
#undef STG

  const long Rb = tileM + wm*128 + quad*4;
  const long Cb = tileN + wn*64 + fr;
  if (BF16_OUT){
    ushort* C = (ushort*)Cv;
    #pragma unroll
    for (int mt=0;mt<8;mt++)
      #pragma unroll
      for (int r=0;r<4;r++){
        const long row = Rb + mt*16 + r;
        #pragma unroll
        for (int nt=0;nt<4;nt++)
          C[row*(long)N + Cb + nt*16] = f2bf(acc[mt][nt][r]);
      }
  } else {
    float* C = (float*)Cv;
    #pragma unroll
    for (int mt=0;mt<8;mt++)
      #pragma unroll
      for (int r=0;r<4;r++){
        const long row = Rb + mt*16 + r;
        #pragma unroll
        for (int nt=0;nt<4;nt++)
          C[row*(long)N + Cb + nt*16] = acc[mt][nt][r];
      }
  }
}

// ============ 256x128-tile 8-phase GEMM (for N=2048 out-proj) ============
// 8 waves (2Mx4N, 32 cols/wave), BK=64, LDS/buf = {A0,A1,B}x8192, counted vmcnt(4).
template<int BF16_OUT>
__global__ __launch_bounds__(512, 2) void gemm256n128(const ushort* __restrict__ A,
                                                      const ushort* __restrict__ B,
                                                      void* __restrict__ Cv,
                                                      int M, int N, int K,
                                                      int rpx, int cpx){
  __shared__ ushort smem[49152];   // [buf2][A0,A1,B][8192]
  __shared__ ushort dummy[4096];
  const int tid = threadIdx.x, w = tid>>6, lane = tid&63;
  const int fr = lane&15, quad = lane>>4;
  const int wm = w>>2, wn = w&3;
  const int NT = K>>6;

  const int nbn = N>>7;
  const int bid = blockIdx.x;
  const int xcd = bid & 7, idx = bid >> 3;
  const int CGn = nbn / cpx;
  const int rgrp = xcd / CGn, cgrp = xcd % CGn;
  const int rloc = idx % rpx, cloc = idx / rpx;
  const long tileM = (long)(rgrp*rpx + rloc) << 8;
  const long tileN = (long)(cgrp*cpx + cloc) << 7;

  const int rr  = (tid&63)>>2;
  const int cc  = ((tid&3)*8) ^ ((rr&8)?16:0);
  const int row0 = (w>>1)*16 + rr;                   // rows 0..63
  const int col0 = (w&1)*32 + cc;
  const long off0 = (long)row0*K + col0;
  const long h64 = 64l*K;

  const ushort* pA0 = A + tileM*K + off0;
  const ushort* pA1 = pA0 + 128l*K;
  const ushort* pB0 = B + tileN*K + off0;

  const int dw = w*512;
  ushort* dmy = dummy + dw;

#define ST_A0(bb,tt) do{ if((tt)<NT){ const long kk=(long)(tt)<<6; \
    gl_lds16(pA0+kk, smem+(bb)*24576+dw);        gl_lds16(pA1+kk, smem+(bb)*24576+8192+dw);} \
    else { gl_lds16(pA0, dmy); gl_lds16(pA1, dmy);} }while(0)
#define ST_A1(bb,tt) do{ if((tt)<NT){ const long kk=((long)(tt)<<6)+h64; \
    gl_lds16(pA0+kk, smem+(bb)*24576+4096+dw);   gl_lds16(pA1+kk, smem+(bb)*24576+12288+dw);} \
    else { gl_lds16(pA0, dmy); gl_lds16(pA1, dmy);} }while(0)
#define ST_B(bb,tt) do{ if((tt)<NT){ const long kk=(long)(tt)<<6; \
    gl_lds16(pB0+kk, smem+(bb)*24576+16384+dw);  gl_lds16(pB0+kk+h64, smem+(bb)*24576+20480+dw);} \
    else { gl_lds16(pB0, dmy); gl_lds16(pB0, dmy);} }while(0)

  const int baseF = fr*32 + ((quad*8) ^ ((fr&8)?16:0));

  f32x4 acc[8][2];
  #pragma unroll
  for (int i=0;i<8;i++)
    #pragma unroll
    for (int j=0;j<2;j++) acc[i][j] = (f32x4){0.f,0.f,0.f,0.f};

  // prologue: t0 fully (6 loads), t1 A0+B (4 loads); vmcnt(4) drains t0.
  ST_A0(0,0); ST_B(0,0); ST_A1(0,0);
  ST_A0(1,1); ST_B(1,1);
  VMC4();
  SBAR();

  #pragma unroll 2
  for (int t=0; t<NT; ++t){
    const int bs = t&1;
    const ushort* SA = smem + bs*24576 + wm*8192;
    const ushort* SB = smem + bs*24576 + 16384;
    s16x8 af[4][2], bl[2], bh[2];
    // ---- phase 1: read A rows0-63 + B nt0; stage A1(t+1) ----
    #pragma unroll
    for (int mt=0;mt<4;mt++)
      #pragma unroll
      for (int ks=0;ks<2;ks++)
        af[mt][ks] = *(const s16x8*)(SA + ((mt*2+ks)<<9) + baseF);
    #pragma unroll
    for (int ks=0;ks<2;ks++)
      bl[ks] = *(const s16x8*)(SB + (((wn*2+0)*2+ks)<<9) + baseF);
    ST_A1(bs^1, t+1);
    SBAR(); LGKM0();
    __builtin_amdgcn_s_setprio(1);
    #pragma unroll
    for (int mt=0;mt<4;mt++){
      acc[mt][0] = MFMA16(af[mt][0], bl[0], acc[mt][0]);
      acc[mt][0] = MFMA16(af[mt][1], bl[1], acc[mt][0]);
    }
    __builtin_amdgcn_s_setprio(0);
    SBAR();
    // ---- phase 2: read B nt1; stage A0(t+2) ----
    #pragma unroll
    for (int ks=0;ks<2;ks++)
      bh[ks] = *(const s16x8*)(SB + (((wn*2+1)*2+ks)<<9) + baseF);
    ST_A0(bs, t+2);
    SBAR(); LGKM0();
    __builtin_amdgcn_s_setprio(1);
    #pragma unroll
    for (int mt=0;mt<4;mt++){
      acc[mt][1] = MFMA16(af[mt][0], bh[0], acc[mt][1]);
      acc[mt][1] = MFMA16(af[mt][1], bh[1], acc[mt][1]);
    }
    __builtin_amdgcn_s_setprio(0);
    SBAR();
    // ---- phase 3: read A rows64-127; stage B(t+2) ----
    #pragma unroll
    for (int mt=0;mt<4;mt++)
      #pragma unroll
      for (int ks=0;ks<2;ks++)
        af[mt][ks] = *(const s16x8*)(SA + (((4+mt)*2+ks)<<9) + baseF);
    ST_B(bs, t+2);
    SBAR(); LGKM0();
    __builtin_amdgcn_s_setprio(1);
    #pragma unroll
    for (int mt=0;mt<4;mt++){
      acc[4+mt][0] = MFMA16(af[mt][0], bl[0], acc[4+mt][0]);
      acc[4+mt][0] = MFMA16(af[mt][1], bl[1], acc[4+mt][0]);
    }
    __builtin_amdgcn_s_setprio(0);
    SBAR();
    // ---- phase 4: no reads/stage; counted vmcnt at K-tile boundary ----
    __builtin_amdgcn_s_setprio(1);
    #pragma unroll
    for (int mt=0;mt<4;mt++){
      acc[4+mt][1] = MFMA16(af[mt][0], bh[0], acc[4+mt][1]);
      acc[4+mt][1] = MFMA16(af[mt][1], bh[1], acc[4+mt][1]);
    }
    __builtin_amdgcn_s_setprio(0);
    VMC4();
    SBAR();
  }
#undef ST_A0
#undef ST_A1
#undef ST_B

  const long Rb = tileM + wm*128 + quad*4;
  const long Cb = tileN + wn*32 + fr;
  if (BF16_OUT){
    ushort* C = (ushort*)Cv;
    #pragma unroll
    for (int mt=0;mt<8;mt++)
      #pragma unroll
      for (int r=0;r<4;r++){
        const long row = Rb + mt*16 + r;
        #pragma unroll
        for (int nt=0;nt<2;nt++)
          C[row*(long)N + Cb + nt*16] = f2bf(acc[mt][nt][r]);
      }
  } else {
    float* C = (float*)Cv;
    #pragma unroll
    for (int mt=0;mt<8;mt++)
      #pragma unroll
      for (int r=0;r<4;r++){
        const long row = Rb + mt*16 + r;
        #pragma unroll
        for (int nt=0;nt<2;nt++)
          C[row*(long)N + Cb + nt*16] = acc[mt][nt][r];
      }
  }
}

// ---------------- bf16 MFMA GEMM (128^2 tile, for small-N shapes) ----------------
template<int BF16_OUT>
__global__ __launch_bounds__(256, 2) void gemm_bt(const ushort* __restrict__ A,
                                                  const ushort* __restrict__ B,
                                                  void* __restrict__ Cv,
                                                  int M, int N, int K){
  __shared__ ushort As[128*32];
  __shared__ ushort Bs[128*32];
  const int nb = N >> 7;
  const int tile_m = (blockIdx.x / nb) << 7;
  const int tile_n = (blockIdx.x % nb) << 7;
  const int tid  = threadIdx.x;
  const int w    = tid >> 6;
  const int lane = tid & 63;

  const int ca = w*2;
  const long rowA = tile_m + ca*16 + (lane>>2);
  const long rowB = tile_n + ca*16 + (lane>>2);
  const int  colE = (lane&3)*8;
  const ushort* pA0 = A + rowA*(long)K + colE;
  const ushort* pA1 = pA0 + 16l*K;
  const ushort* pB0 = B + rowB*(long)K + colE;
  const ushort* pB1 = pB0 + 16l*K;
  ushort* lA0 = As + ca*512;
  ushort* lA1 = As + ca*512 + 512;
  ushort* lB0 = Bs + ca*512;
  ushort* lB1 = Bs + ca*512 + 512;

  const int wr = (w>>1)<<6;
  const int wc = (w&1)<<6;
  const int fr = lane & 15;
  const int fk = (lane>>4)<<3;

  f32x4 acc[4][4];
  #pragma unroll
  for (int i=0;i<4;i++)
    #pragma unroll
    for (int j=0;j<4;j++) acc[i][j] = (f32x4){0.f,0.f,0.f,0.f};

  for (int k0 = 0; k0 < K; k0 += 32){
    __syncthreads();
    gl_lds16(pA0, lA0);
    gl_lds16(pA1, lA1);
    gl_lds16(pB0, lB0);
    gl_lds16(pB1, lB1);
    __syncthreads();
    s16x8 af[4], bfr[4];
    #pragma unroll
    for (int t=0;t<4;t++){
      af[t]  = *(const s16x8*)(As + (wr + t*16 + fr)*32 + fk);
      bfr[t] = *(const s16x8*)(Bs + (wc + t*16 + fr)*32 + fk);
    }
    #pragma unroll
    for (int mt=0;mt<4;mt++)
      #pragma unroll
      for (int nt=0;nt<4;nt++)
        acc[mt][nt] = MFMA16(af[mt], bfr[nt], acc[mt][nt]);
    pA0 += 32; pA1 += 32; pB0 += 32; pB1 += 32;
  }

  const int crow = tile_m + wr + ((lane>>4)<<2);
  const int ccol = tile_n + wc + (lane&15);
  if (BF16_OUT){
    ushort* C = (ushort*)Cv;
    #pragma unroll
    for (int mt=0;mt<4;mt++)
      #pragma unroll
      for (int r=0;r<4;r++){
        long row = crow + mt*16 + r;
        #pragma unroll
        for (int nt=0;nt<4;nt++)
          C[row*(long)N + ccol + nt*16] = f2bf(acc[mt][nt][r]);
      }
  } else {
    float* C = (float*)Cv;
    #pragma unroll
    for (int mt=0;mt<4;mt++)
      #pragma unroll
      for (int r=0;r<4;r++){
        long row = crow + mt*16 + r;
        #pragma unroll
        for (int nt=0;nt<4;nt++)
          C[row*(long)N + ccol + nt*16] = acc[mt][nt][r];
      }
  }
}

// ---------------- beta / log-decay epilogue from bapr[4096][128] ----------------
__global__ __launch_bounds__(256) void ba_post(const float* __restrict__ bapr,
    const float* __restrict__ dtb, const float* __restrict__ alog,
    float* __restrict__ beta, float* __restrict__ glog){
  const int idx = blockIdx.x*256 + threadIdx.x;     // over 4096*64
  const int m = idx >> 6, j = idx & 63;
  const float v = bapr[(long)m*128 + j];
  if (j < 32){
    beta[(long)m*32 + j] = 1.f/(1.f+expf(-v));
  } else {
    const int n = j - 32;
    float ap = v + dtb[n];
    float sp = (ap > 20.f) ? ap : log1pf(expf(ap));
    glog[(long)m*32 + n] = -expf(alog[n]) * sp;     // log decay g
  }
}

// ------- causal depthwise conv(K=4) + silu + l2norm(q,k), register sliding window -------
__global__ __launch_bounds__(256) void conv_qkv2(const ushort* __restrict__ mixed,
    const float* __restrict__ convw, ushort* __restrict__ qn, ushort* __restrict__ kn,
    ushort* __restrict__ vv){
  const long m0 = (long)blockIdx.x * 32;
  const int ct = blockIdx.y;
  const int ch = (ct<<11) + threadIdx.x*8;
  const ushort* base = mixed + ch;

  ushort* outp; int mode; float qsc = 1.f;
  if (ct == 0){ outp = qn + ch;        mode = 0; qsc = 0.08838834764831845f; }
  else if (ct == 1){ outp = kn + (ch-2048); mode = 1; }
  else { outp = vv + (ch-4096); mode = 2; }

  float cw0[8], cw1[8], cw2[8], cw3[8];
  #pragma unroll
  for (int e=0;e<8;e++){
    float4 wv = *(const float4*)(convw + (long)(ch+e)*4);
    cw0[e]=wv.x; cw1[e]=wv.y; cw2[e]=wv.z; cw3[e]=wv.w;
  }

#define LDROW(PTR, R) do{ s16x8 _v = *(const s16x8*)(PTR); \
    _Pragma("unroll") \
    for (int e=0;e<8;e++) R[e] = bf2f((ushort)_v[e]); }while(0)

#define STEP(P0,P1,P2,P3,MR) do{ \
    float y[8]; float ss = 0.f; \
    _Pragma("unroll") \
    for (int e=0;e<8;e++){ \
      float a = P0[e]*cw0[e]; \
      a += P1[e]*cw1[e]; \
      a += P2[e]*cw2[e]; \
      a += P3[e]*cw3[e]; \
      float sv = a / (1.f + expf(-a)); \
      y[e] = sv; ss += sv*sv; } \
    if (mode < 2){ \
      ss += __shfl_xor(ss,1); ss += __shfl_xor(ss,2); \
      ss += __shfl_xor(ss,4); ss += __shfl_xor(ss,8); \
      const float r_ = rsqrtf(ss + 1e-6f) * qsc; \
      s16x8 ov; \
      _Pragma("unroll") \
      for (int e=0;e<8;e++) ov[e] = (short)f2bf(y[e]*r_); \
      *(s16x8*)(outp + (MR)*2048) = ov; \
    } else { \
      s16x8 ov; \
      _Pragma("unroll") \
      for (int e=0;e<8;e++) ov[e] = (short)f2bf(y[e]); \
      *(s16x8*)(outp + (MR)*4096) = ov; \
    } \
  }while(0)

  float w3[8], w2[8], w1[8];      // rows m-3, m-2, m-1
  if (((int)m0 & 2047) == 0){
    #pragma unroll
    for (int e=0;e<8;e++){ w3[e]=0.f; w2[e]=0.f; w1[e]=0.f; }
  } else {
    LDROW(base + (m0-3)*8192, w3);
    LDROW(base + (m0-2)*8192, w2);
    LDROW(base + (m0-1)*8192, w1);
  }

  long m = m0;
  for (int it=0; it<8; ++it){
    float r0[8], r1[8], r2[8], r3[8];
    LDROW(base + (m+0)*8192, r0);
    LDROW(base + (m+1)*8192, r1);
    LDROW(base + (m+2)*8192, r2);
    LDROW(base + (m+3)*8192, r3);
    STEP(w3,w2,w1,r0, m+0);
    STEP(w2,w1,r0,r1, m+1);
    STEP(w1,r0,r1,r2, m+2);
    STEP(r0,r1,r2,r3, m+3);
    #pragma unroll
    for (int e=0;e<8;e++){ w3[e]=r1[e]; w2[e]=r2[e]; w1[e]=r3[e]; }
    m += 4;
  }
#undef LDROW
#undef STEP
}

// ---------------- pass 1: per-chunk T=(I+Ahat)^-1, M, cumLg (parallel, 4096 blocks) --------
__global__ __launch_bounds__(256) void chunk_prep(
    const ushort* __restrict__ qn, const ushort* __restrict__ kn,
    const float* __restrict__ beta, const float* __restrict__ glog,
    ushort* __restrict__ Tg, ushort* __restrict__ Mg, float* __restrict__ cumLgG){
  const int bid = blockIdx.x;
  const int bh = bid >> 6, ch = bid & 63;
  const int b = bh>>5, h = bh&31, hq = h>>1;
  const long tch = (long)b*2048 + ch*32;
  const int tid = threadIdx.x, w = tid>>6, lane = tid&63;
  const int quad = lane>>4, l15 = lane&15;

  __shared__ __attribute__((aligned(16))) ushort Kl[32][136];
  __shared__ __attribute__((aligned(16))) ushort Ql[32][136];
  __shared__ float Asl[32][33];
  __shared__ float Lgl[32], Btl[32];

  const int sc = tid>>3, ss = (tid&7)*16;
  {
    const ushort* kp = kn + (tch+sc)*2048 + hq*128 + ss;
    const ushort* qp = qn + (tch+sc)*2048 + hq*128 + ss;
    *(u32x4*)&Kl[sc][ss] = *(const u32x4*)kp; *(u32x4*)&Kl[sc][ss+8] = *(const u32x4*)(kp+8);
    *(u32x4*)&Ql[sc][ss] = *(const u32x4*)qp; *(u32x4*)&Ql[sc][ss+8] = *(const u32x4*)(qp+8);
  }
  if (tid < 64){
    const int c = lane & 31;
    float gv = glog[(tch + c)*32 + h];
    float bv = beta[(tch + c)*32 + h];
    #pragma unroll
    for (int off=1; off<32; off<<=1){
      float t = __shfl_up(gv, off);
      if ((lane & 31) >= off) gv += t;
    }
    if (lane < 32){ Lgl[c] = gv; Btl[c] = bv; cumLgG[(long)bid*32 + c] = gv; }
  }
  __syncthreads();

  const int mt = w>>1, nt = w&1;
  s16x8 ka[4], qa[4], kb[4];
  #pragma unroll
  for (int ks=0; ks<4; ks++){
    ka[ks] = *(const s16x8*)&Kl[mt*16+l15][ks*32 + quad*8];
    qa[ks] = *(const s16x8*)&Ql[mt*16+l15][ks*32 + quad*8];
    kb[ks] = *(const s16x8*)&Kl[nt*16+l15][ks*32 + quad*8];
  }
  f32x4 accK = (f32x4){0.f,0.f,0.f,0.f}, accQ = (f32x4){0.f,0.f,0.f,0.f};
  #pragma unroll
  for (int ks=0; ks<4; ks++){
    accK = MFMA16(ka[ks], kb[ks], accK);
    accQ = MFMA16(qa[ks], kb[ks], accQ);
  }
  const int j = nt*16 + l15;
  const float Lgj = Lgl[j];
  #pragma unroll
  for (int i=0;i<4;i++){
    const int r = mt*16 + quad*4 + i;
    const float e = expf(Lgl[r]-Lgj);
    Asl[r][j] = (r>j) ? -Btl[r]*e*accK[i] : 0.f;   // = -Ahat
    Mg[(long)bid*1024 + r*32 + j] = (r>=j) ? f2bf(e*accQ[i]) : (ushort)0;
  }
  __syncthreads();

  if (tid < 32){
    const int jc = tid;
    float tc[32];
    #pragma unroll
    for (int c=0;c<32;c++){
      float acc = (c==jc) ? 1.f : 0.f;
      #pragma unroll
      for (int i2=0;i2<c;i2++) acc = fmaf(Asl[c][i2], tc[i2], acc);
      tc[c] = acc;
      Tg[(long)bid*1024 + c*32 + jc] = f2bf(acc);
    }
  }
}

// ---------------- pass 2: sequential inter-chunk recurrence, latency-optimized ----------------
__global__ __launch_bounds__(256, 2) void chunk_scan3(
    const ushort* __restrict__ qn, const ushort* __restrict__ kn,
    const ushort* __restrict__ vv, const float* __restrict__ beta,
    const float* __restrict__ cumLg, const ushort* __restrict__ Tg,
    const ushort* __restrict__ Mg, float* __restrict__ o){
  const int bh = blockIdx.x & 63, sl = blockIdx.x >> 6;
  const int b = bh>>5, h = bh&31, hq = h>>1;
  const int dv0 = sl<<4;
  const int tid = threadIdx.x, w = tid>>6, lane = tid&63;
  const int quad = lane>>4, l15 = lane&15;
  const int rt = w&1, kq = w>>1;

  __shared__ __attribute__((aligned(16))) ushort STl[16][136];  // S^T [dv][dk]
  __shared__ __attribute__((aligned(16))) ushort B0T[16][40];   // b0^T [dv][row]
  __shared__ __attribute__((aligned(16))) ushort DT[16][40];    // D   [dv][row]
  __shared__ float Btf[32], eLgl[32], eDf[32];

  const ushort* pKQ = (kq ? qn : kn) + ((long)b*2048 + rt*16 + l15)*2048 + hq*128 + quad*8;
  const ushort* pKT = kn + ((long)b*2048 + quad*8)*2048 + hq*128 + w*32 + l15;
  const ushort* pV  = vv + ((long)b*2048 + rt*16 + quad*4)*4096 + h*128 + dv0 + l15;
  const ushort* pTM = (kq ? Mg : Tg) + (long)bh*65536 + (rt*16 + l15)*32 + quad*8;
  const long pbBase = (long)bh*2048 + tid;
  const float* betaP = beta + ((long)b*2048 + tid)*32 + h;

  s16x8 cKQ[4], nKQ[4], cK0, cK1, nK0, nK1, cTM, nTM;
  ushort cV0=0,cV1=0,cV2=0,cV3=0, nV0=0,nV1=0,nV2=0,nV3=0;
  float cLg = 0.f, nLg = 0.f, cBt = 0.f, nBt = 0.f;

  f32x4 S0 = (f32x4){0.f,0.f,0.f,0.f}, S1 = (f32x4){0.f,0.f,0.f,0.f};

#define LOADCH(PKQ,PK0,PK1,PV0,PV1,PV2,PV3,PTMv,PLG,PBT,CH) do{ \
    const long co = (long)(CH)*65536; \
    _Pragma("unroll") \
    for (int ks=0; ks<4; ks++) PKQ[ks] = *(const s16x8*)(pKQ + co + ks*32); \
    _Pragma("unroll") \
    for (int e=0; e<8; e++){ \
      PK0[e] = (short)pKT[co + (long)e*2048]; \
      PK1[e] = (short)pKT[co + (long)e*2048 + 16]; } \
    if (kq == 0){ \
      const long vo = (long)(CH)*131072; \
      PV0 = pV[vo]; PV1 = pV[vo+4096]; PV2 = pV[vo+8192]; PV3 = pV[vo+12288]; } \
    PTMv = *(const s16x8*)(pTM + (long)(CH)*1024); \
    if (tid < 32){ PLG = cumLg[pbBase + (long)(CH)*32]; PBT = betaP[(long)(CH)*1024]; } \
  }while(0)

  LOADCH(cKQ, cK0, cK1, cV0,cV1,cV2,cV3, cTM, cLg, cBt, 0);

  for (int ch=0; ch<64; ch++){
    const long tch = (long)b*2048 + ch*32;
    LOADCH(nKQ, nK0, nK1, nV0,nV1,nV2,nV3, nTM, nLg, nBt, (ch<63)?(ch+1):63);
    if (tid < 32){
      float lgC = __shfl(cLg, 31);
      Btf[tid] = cBt;
      eLgl[tid] = expf(cLg);
      eDf[tid]  = expf(lgC - cLg);
    }
    {
      ushort4 p0, p1;
      p0.x=f2bf(S0[0]); p0.y=f2bf(S0[1]); p0.z=f2bf(S0[2]); p0.w=f2bf(S0[3]);
      p1.x=f2bf(S1[0]); p1.y=f2bf(S1[1]); p1.z=f2bf(S1[2]); p1.w=f2bf(S1[3]);
      *(ushort4*)&STl[l15][w*32 + quad*4]      = p0;
      *(ushort4*)&STl[l15][w*32 + 16 + quad*4] = p1;
    }
    __syncthreads();
    f32x4 acc = (f32x4){0.f,0.f,0.f,0.f};
    #pragma unroll
    for (int ks=0; ks<4; ks++){
      s16x8 sb = *(const s16x8*)&STl[l15][ks*32 + quad*8];
      acc = MFMA16(cKQ[ks], sb, acc);
    }
    if (kq == 0){
      const int c0r = rt*16 + quad*4;
      ushort4 pb;
      pb.x = f2bf(Btf[c0r+0]*(bf2f(cV0) - eLgl[c0r+0]*acc[0]));
      pb.y = f2bf(Btf[c0r+1]*(bf2f(cV1) - eLgl[c0r+1]*acc[1]));
      pb.z = f2bf(Btf[c0r+2]*(bf2f(cV2) - eLgl[c0r+2]*acc[2]));
      pb.w = f2bf(Btf[c0r+3]*(bf2f(cV3) - eLgl[c0r+3]*acc[3]));
      *(ushort4*)&B0T[l15][rt*16 + quad*4] = pb;
    } else {
      #pragma unroll
      for (int i=0;i<4;i++) acc[i] *= eLgl[rt*16 + quad*4 + i];
    }
    __syncthreads();
    const float eC = eLgl[31];
    s16x8 kta0, kta1;
    #pragma unroll
    for (int e=0;e<8;e++){
      const float ed = eDf[quad*8 + e];
      kta0[e] = (short)f2bf(bf2f((ushort)cK0[e])*ed);
      kta1[e] = (short)f2bf(bf2f((ushort)cK1[e])*ed);
    }
    if (kq == 0){
      s16x8 a = *(const s16x8*)&B0T[l15][quad*8];
      f32x4 Dt = MFMA16(a, cTM, ((f32x4){0.f,0.f,0.f,0.f}));
      #pragma unroll
      for (int i=0;i<4;i++)
        DT[quad*4+i][rt*16 + l15] = f2bf(Dt[i]);
    }
    __syncthreads();
    s16x8 df = *(const s16x8*)&DT[l15][quad*8];
    if (kq == 1){
      f32x4 O = MFMA16(cTM, df, acc);
      #pragma unroll
      for (int i=0;i<4;i++)
        o[(tch + rt*16 + quad*4 + i)*4096 + h*128 + dv0 + l15] = O[i];
    }
    f32x4 t0, t1;
    #pragma unroll
    for (int i=0;i<4;i++){ t0[i] = S0[i]*eC; t1[i] = S1[i]*eC; }
    S0 = MFMA16(kta0, df, t0);
    S1 = MFMA16(kta1, df, t1);
    #pragma unroll
    for (int ks=0; ks<4; ks++) cKQ[ks] = nKQ[ks];
    cK0 = nK0; cK1 = nK1; cTM = nTM;
    cV0 = nV0; cV1 = nV1; cV2 = nV2; cV3 = nV3;
    cLg = nLg; cBt = nBt;
  }
#undef LOADCH
}

// ---------------- RMSNorm(gated) + silu(z) gate, bf16 out ----------------
__global__ __launch_bounds__(128) void norm_gate(const float* __restrict__ o,
    const ushort* __restrict__ z, const float* __restrict__ normw,
    ushort* __restrict__ og){
  const long mh = blockIdx.x;
  const int d = threadIdx.x;
  float x = o[mh*128 + d];
  float ss = x*x;
  #pragma unroll
  for (int off=32; off; off>>=1) ss += __shfl_xor(ss, off);
  __shared__ float w2[2];
  if ((d&63)==0) w2[d>>6] = ss;
  __syncthreads();
  float r = rsqrtf((w2[0]+w2[1])*(1.f/128.f) + 1e-6f);
  float zz = bf2f(z[mh*128 + d]);
  float sil = zz / (1.f + expf(-zz));
  og[mh*128 + d] = f2bf(x*r*normw[d]*sil);
}

extern "C" void kernel_launch(void* const* d_in, const int* in_sizes, int n_in,
                              void* d_out, int out_size, void* d_ws, size_t ws_size,
                              hipStream_t stream){
  const float* hs    = (const float*)d_in[0];
  const float* Wqkv  = (const float*)d_in[1];
  const float* Wz    = (const float*)d_in[2];
  const float* Wb    = (const float*)d_in[3];
  const float* Wa    = (const float*)d_in[4];
  const float* convw = (const float*)d_in[5];
  const float* normw = (const float*)d_in[6];
  const float* Wout  = (const float*)d_in[7];
  const float* dtb   = (const float*)d_in[8];
  const float* alog  = (const float*)d_in[9];

  char* ws = (char*)d_ws;
  ushort* hsb   = (ushort*)(ws);                 // [0,16M)    hs bf16  -> later kn
  ushort* wqb   = (ushort*)(ws + (16l<<20));     // [16,48M)   Wqkv bf16 -> later v -> og
  ushort* wzb   = (ushort*)(ws + (48l<<20));     // [48,64M)   Wz bf16  -> later qn
  ushort* wob   = (ushort*)(ws + (64l<<20));     // [64,80M)   Wout bf16
  ushort* mixed = (ushort*)(ws + (80l<<20));     // [80,144M)  mixed bf16 -> later o_raw f32
  ushort* zb    = (ushort*)(ws + (144l<<20));    // [144,176M) z bf16
  float*  beta  = (float*)(ws + (176l<<20));     // 512K
  float*  cumLg = (float*)(ws + (176l<<20) + (512l<<10)); // 512K
  float*  glog  = (float*)(ws + (177l<<20));     // 512K
  ushort* Tg    = (ushort*)(ws + (178l<<20));    // [178,186M) T bf16
  ushort* Mg    = (ushort*)(ws + (186l<<20));    // [186,194M) M bf16
  ushort* wbab  = (ushort*)(ws + (194l<<20));    // [194,194.5M) W_ba bf16 [128][2048]
  float*  bapr  = (float*)(ws + (195l<<20));     // [195,197M) ba projection fp32 [4096][128]
  ushort* kn = hsb;  ushort* qn = wzb;  ushort* vvp = wqb;  ushort* og = wqb;
  float*  o_raw = (float*)mixed;

  cvt_bf16<<<8192,  256, 0, stream>>>(hs,   hsb);
  cvt_bf16<<<16384, 256, 0, stream>>>(Wqkv, wqb);
  cvt_bf16<<<8192,  256, 0, stream>>>(Wz,   wzb);
  cvt_bf16<<<8192,  256, 0, stream>>>(Wout, wob);
  cvt_bf16<<<64,    256, 0, stream>>>(Wb,   wbab);          // rows 0..31
  cvt_bf16<<<64,    256, 0, stream>>>(Wa,   wbab + 65536);  // rows 32..63 (64..127 garbage, unread)

  gemm256<1><<<512, 512, 0, stream>>>(hsb, wqb, (void*)mixed, 4096, 8192, 2048, 4, 16);
  gemm256<1><<<256, 512, 0, stream>>>(hsb, wzb, (void*)zb,    4096, 4096, 2048, 4, 8);
  gemm_bt<0><<<32*1,  256, 0, stream>>>(hsb, wbab, (void*)bapr, 4096, 128,  2048);
  ba_post<<<1024, 256, 0, stream>>>(bapr, dtb, alog, beta, glog);

  conv_qkv2<<<dim3(128,4), 256, 0, stream>>>(mixed, convw, qn, kn, vvp);
  chunk_prep<<<4096, 256, 0, stream>>>(qn, kn, beta, glog, Tg, Mg, cumLg);
  chunk_scan3<<<512, 256, 0, stream>>>(qn, kn, vvp, beta, cumLg, Tg, Mg, o_raw);
  norm_gate<<<131072, 128, 0, stream>>>(o_raw, zb, normw, og);

  gemm256n128<0><<<256, 512, 0, stream>>>(og, wob, d_out, 4096, 2048, 4096, 4, 8);
}

// Round 7
// 655.610 us; speedup vs baseline: 1.0863x; 1.0863x over previous
//
#include <hip/hip_runtime.h>
#include <hip/hip_bf16.h>
#include <math.h>

#define DEVI __device__ __forceinline__

typedef __attribute__((ext_vector_type(4))) float f32x4;
typedef __attribute__((ext_vector_type(8))) short s16x8;
typedef __attribute__((ext_vector_type(4))) unsigned int u32x4;

DEVI float bf2f(ushort u){ union{unsigned int i; float f;} x; x.i = ((unsigned int)u)<<16; return x.f; }
DEVI ushort f2bf(float f){ union{float f; unsigned int i;} x; x.f = f;
  unsigned int r = x.i + 0x7fffu + ((x.i>>16)&1u); return (ushort)(r>>16); }

#define MFMA16(a,b,c) __builtin_amdgcn_mfma_f32_16x16x32_bf16(a,b,c,0,0,0)

// ---------------- fp32 -> bf16 convert, 4 elems/thread ----------------
__global__ __launch_bounds__(256) void cvt_bf16(const float* __restrict__ in, ushort* __restrict__ out){
  int i = blockIdx.x*256 + threadIdx.x;
  float4 v = ((const float4*)in)[i];
  ushort4 o; o.x = f2bf(v.x); o.y = f2bf(v.y); o.z = f2bf(v.z); o.w = f2bf(v.w);
  ((ushort4*)out)[i] = o;
}

DEVI void gl_lds16(const ushort* g, ushort* l){
  __builtin_amdgcn_global_load_lds((const __attribute__((address_space(1))) void*)g,
                                   (__attribute__((address_space(3))) void*)l, 16, 0, 0);
}

#define SBAR() __builtin_amdgcn_s_barrier()
#define LGKM0() do{ asm volatile("s_waitcnt lgkmcnt(0)" ::: "memory"); __builtin_amdgcn_sched_barrier(0); }while(0)
#define VMC6() asm volatile("s_waitcnt vmcnt(6)" ::: "memory")
#define VMC4() asm volatile("s_waitcnt vmcnt(4)" ::: "memory")

// ============ 256x256-tile 8-phase GEMM: C[M,N] = A[M,K] * B[N,K]^T ============
// (round-5 version — best measured: 140us qkv, MfmaUtil 42.6, FETCH 100MB)
// XCD-region swizzle: XCD covers rpx tile-rows x cpx tile-cols, col-major walk.
template<int BF16_OUT>
__global__ __launch_bounds__(512, 2) void gemm256(const ushort* __restrict__ A,
                                                  const ushort* __restrict__ B,
                                                  void* __restrict__ Cv,
                                                  int M, int N, int K,
                                                  int rpx, int cpx){
  __shared__ ushort smem[65536];   // [buf2][slot4: A0,A1,B0,B1][8192]
  __shared__ ushort dummy[4096];
  const int tid = threadIdx.x, w = tid>>6, lane = tid&63;
  const int fr = lane&15, quad = lane>>4;
  const int wm = w>>2, wn = w&3;
  const int NT = K>>6;

  const int nbn = N>>8;
  const int bid = blockIdx.x;
  const int xcd = bid & 7, idx = bid >> 3;
  const int CGn = nbn / cpx;
  const int rgrp = xcd / CGn, cgrp = xcd % CGn;
  const int rloc = idx % rpx, cloc = idx / rpx;
  const long tileM = (long)(rgrp*rpx + rloc) << 8;
  const long tileN = (long)(cgrp*cpx + cloc) << 8;

  const int rr  = (tid&63)>>2;                       // 0..15
  const int cc  = ((tid&3)*8) ^ ((rr&8)?16:0);
  const int row0 = (w>>1)*16 + rr;                   // rows 0..63
  const int col0 = (w&1)*32 + cc;
  const long off0 = (long)row0*K + col0;
  const long h64 = 64l*K;

  const ushort* pA0 = A + tileM*K + off0;
  const ushort* pA1 = pA0 + 128l*K;
  const ushort* pB0 = B + tileN*K + off0;
  const ushort* pB1 = pB0 + 128l*K;

  const int dw = w*512;
  ushort* dmy = dummy + dw;

#define ST_A0(bb,tt) do{ if((tt)<NT){ const long kk=(long)(tt)<<6; \
    gl_lds16(pA0+kk, smem+(bb)*32768+dw);        gl_lds16(pA1+kk, smem+(bb)*32768+8192+dw);} \
    else { gl_lds16(pA0, dmy); gl_lds16(pA1, dmy);} }while(0)
#define ST_A1(bb,tt) do{ if((tt)<NT){ const long kk=((long)(tt)<<6)+h64; \
    gl_lds16(pA0+kk, smem+(bb)*32768+4096+dw);   gl_lds16(pA1+kk, smem+(bb)*32768+12288+dw);} \
    else { gl_lds16(pA0, dmy); gl_lds16(pA1, dmy);} }while(0)
#define ST_B0(bb,tt) do{ if((tt)<NT){ const long kk=(long)(tt)<<6; \
    gl_lds16(pB0+kk, smem+(bb)*32768+16384+dw);  gl_lds16(pB1+kk, smem+(bb)*32768+24576+dw);} \
    else { gl_lds16(pB0, dmy); gl_lds16(pB1, dmy);} }while(0)
#define ST_B1(bb,tt) do{ if((tt)<NT){ const long kk=((long)(tt)<<6)+h64; \
    gl_lds16(pB0+kk, smem+(bb)*32768+20480+dw);  gl_lds16(pB1+kk, smem+(bb)*32768+28672+dw);} \
    else { gl_lds16(pB0, dmy); gl_lds16(pB1, dmy);} }while(0)

  const int baseF = fr*32 + ((quad*8) ^ ((fr&8)?16:0));
  const int sB = (wn&1)*4;

  f32x4 acc[8][4];
  #pragma unroll
  for (int i=0;i<8;i++)
    #pragma unroll
    for (int j=0;j<4;j++) acc[i][j] = (f32x4){0.f,0.f,0.f,0.f};

  ST_A0(0,0); ST_B0(0,0); ST_B1(0,0); ST_A1(0,0);
  ST_A0(1,1); ST_B0(1,1); ST_B1(1,1);
  VMC6();
  SBAR();

  #pragma unroll 2
  for (int t=0; t<NT; ++t){
    const int bs = t&1;
    const ushort* SA = smem + bs*32768 + wm*8192;
    const ushort* SB = smem + bs*32768 + 16384 + (wn>>1)*8192;
    s16x8 af[4][2], bl[2][2], bh[2][2];
    // ---- phase 1 ----
    #pragma unroll
    for (int mt=0;mt<4;mt++)
      #pragma unroll
      for (int ks=0;ks<2;ks++)
        af[mt][ks] = *(const s16x8*)(SA + ((mt*2+ks)<<9) + baseF);
    #pragma unroll
    for (int nt=0;nt<2;nt++)
      #pragma unroll
      for (int ks=0;ks<2;ks++)
        bl[nt][ks] = *(const s16x8*)(SB + (((sB+nt)*2+ks)<<9) + baseF);
    ST_A1(bs^1, t+1);
    SBAR(); LGKM0();
    __builtin_amdgcn_s_setprio(1);
    #pragma unroll
    for (int mt=0;mt<4;mt++)
      #pragma unroll
      for (int nt=0;nt<2;nt++){
        acc[mt][nt] = MFMA16(af[mt][0], bl[nt][0], acc[mt][nt]);
        acc[mt][nt] = MFMA16(af[mt][1], bl[nt][1], acc[mt][nt]);
      }
    __builtin_amdgcn_s_setprio(0);
    SBAR();
    // ---- phase 2 ----
    #pragma unroll
    for (int nt=0;nt<2;nt++)
      #pragma unroll
      for (int ks=0;ks<2;ks++)
        bh[nt][ks] = *(const s16x8*)(SB + (((sB+2+nt)*2+ks)<<9) + baseF);
    ST_A0(bs, t+2);
    SBAR(); LGKM0();
    __builtin_amdgcn_s_setprio(1);
    #pragma unroll
    for (int mt=0;mt<4;mt++)
      #pragma unroll
      for (int nt=0;nt<2;nt++){
        acc[mt][2+nt] = MFMA16(af[mt][0], bh[nt][0], acc[mt][2+nt]);
        acc[mt][2+nt] = MFMA16(af[mt][1], bh[nt][1], acc[mt][2+nt]);
      }
    __builtin_amdgcn_s_setprio(0);
    SBAR();
    // ---- phase 3 ----
    #pragma unroll
    for (int mt=0;mt<4;mt++)
      #pragma unroll
      for (int ks=0;ks<2;ks++)
        af[mt][ks] = *(const s16x8*)(SA + (((4+mt)*2+ks)<<9) + baseF);
    ST_B0(bs, t+2);
    SBAR(); LGKM0();
    __builtin_amdgcn_s_setprio(1);
    #pragma unroll
    for (int mt=0;mt<4;mt++)
      #pragma unroll
      for (int nt=0;nt<2;nt++){
        acc[4+mt][nt] = MFMA16(af[mt][0], bl[nt][0], acc[4+mt][nt]);
        acc[4+mt][nt] = MFMA16(af[mt][1], bl[nt][1], acc[4+mt][nt]);
      }
    __builtin_amdgcn_s_setprio(0);
    SBAR();
    // ---- phase 4 ----
    ST_B1(bs, t+2);
    SBAR();
    __builtin_amdgcn_s_setprio(1);
    #pragma unroll
    for (int mt=0;mt<4;mt++)
      #pragma unroll
      for (int nt=0;nt<2;nt++){
        acc[4+mt][2+nt] = MFMA16(af[mt][0], bh[nt][0], acc[4+mt][2+nt]);
        acc[4+mt][2+nt] = MFMA16(af[mt][1], bh[nt][1], acc[4+mt][2+nt]);
      }
    __builtin_amdgcn_s_setprio(0);
    VMC6();
    SBAR();
  }
#undef ST_A0
#undef ST_A1
#undef ST_B0
#undef ST_B1

  const long Rb = tileM + wm*128 + quad*4;
  const long Cb = tileN + wn*64 + fr;
  if (BF16_OUT){
    ushort* C = (ushort*)Cv;
    #pragma unroll
    for (int mt=0;mt<8;mt++)
      #pragma unroll
      for (int r=0;r<4;r++){
        const long row = Rb + mt*16 + r;
        #pragma unroll
        for (int nt=0;nt<4;nt++)
          C[row*(long)N + Cb + nt*16] = f2bf(acc[mt][nt][r]);
      }
  } else {
    float* C = (float*)Cv;
    #pragma unroll
    for (int mt=0;mt<8;mt++)
      #pragma unroll
      for (int r=0;r<4;r++){
        const long row = Rb + mt*16 + r;
        #pragma unroll
        for (int nt=0;nt<4;nt++)
          C[row*(long)N + Cb + nt*16] = acc[mt][nt][r];
      }
  }
}

// ============ 256x128-tile 8-phase GEMM (for N=2048 out-proj) ============
template<int BF16_OUT>
__global__ __launch_bounds__(512, 2) void gemm256n128(const ushort* __restrict__ A,
                                                      const ushort* __restrict__ B,
                                                      void* __restrict__ Cv,
                                                      int M, int N, int K,
                                                      int rpx, int cpx){
  __shared__ ushort smem[49152];   // [buf2][A0,A1,B][8192]
  __shared__ ushort dummy[4096];
  const int tid = threadIdx.x, w = tid>>6, lane = tid&63;
  const int fr = lane&15, quad = lane>>4;
  const int wm = w>>2, wn = w&3;
  const int NT = K>>6;

  const int nbn = N>>7;
  const int bid = blockIdx.x;
  const int xcd = bid & 7, idx = bid >> 3;
  const int CGn = nbn / cpx;
  const int rgrp = xcd / CGn, cgrp = xcd % CGn;
  const int rloc = idx % rpx, cloc = idx / rpx;
  const long tileM = (long)(rgrp*rpx + rloc) << 8;
  const long tileN = (long)(cgrp*cpx + cloc) << 7;

  const int rr  = (tid&63)>>2;
  const int cc  = ((tid&3)*8) ^ ((rr&8)?16:0);
  const int row0 = (w>>1)*16 + rr;                   // rows 0..63
  const int col0 = (w&1)*32 + cc;
  const long off0 = (long)row0*K + col0;
  const long h64 = 64l*K;

  const ushort* pA0 = A + tileM*K + off0;
  const ushort* pA1 = pA0 + 128l*K;
  const ushort* pB0 = B + tileN*K + off0;

  const int dw = w*512;
  ushort* dmy = dummy + dw;

#define ST_A0(bb,tt) do{ if((tt)<NT){ const long kk=(long)(tt)<<6; \
    gl_lds16(pA0+kk, smem+(bb)*24576+dw);        gl_lds16(pA1+kk, smem+(bb)*24576+8192+dw);} \
    else { gl_lds16(pA0, dmy); gl_lds16(pA1, dmy);} }while(0)
#define ST_A1(bb,tt) do{ if((tt)<NT){ const long kk=((long)(tt)<<6)+h64; \
    gl_lds16(pA0+kk, smem+(bb)*24576+4096+dw);   gl_lds16(pA1+kk, smem+(bb)*24576+12288+dw);} \
    else { gl_lds16(pA0, dmy); gl_lds16(pA1, dmy);} }while(0)
#define ST_B(bb,tt) do{ if((tt)<NT){ const long kk=(long)(tt)<<6; \
    gl_lds16(pB0+kk, smem+(bb)*24576+16384+dw);  gl_lds16(pB0+kk+h64, smem+(bb)*24576+20480+dw);} \
    else { gl_lds16(pB0, dmy); gl_lds16(pB0, dmy);} }while(0)

  const int baseF = fr*32 + ((quad*8) ^ ((fr&8)?16:0));

  f32x4 acc[8][2];
  #pragma unroll
  for (int i=0;i<8;i++)
    #pragma unroll
    for (int j=0;j<2;j++) acc[i][j] = (f32x4){0.f,0.f,0.f,0.f};

  ST_A0(0,0); ST_B(0,0); ST_A1(0,0);
  ST_A0(1,1); ST_B(1,1);
  VMC4();
  SBAR();

  #pragma unroll 2
  for (int t=0; t<NT; ++t){
    const int bs = t&1;
    const ushort* SA = smem + bs*24576 + wm*8192;
    const ushort* SB = smem + bs*24576 + 16384;
    s16x8 af[4][2], bl[2], bh[2];
    // ---- phase 1: read A rows0-63 + B nt0; stage A1(t+1) ----
    #pragma unroll
    for (int mt=0;mt<4;mt++)
      #pragma unroll
      for (int ks=0;ks<2;ks++)
        af[mt][ks] = *(const s16x8*)(SA + ((mt*2+ks)<<9) + baseF);
    #pragma unroll
    for (int ks=0;ks<2;ks++)
      bl[ks] = *(const s16x8*)(SB + (((wn*2+0)*2+ks)<<9) + baseF);
    ST_A1(bs^1, t+1);
    SBAR(); LGKM0();
    __builtin_amdgcn_s_setprio(1);
    #pragma unroll
    for (int mt=0;mt<4;mt++){
      acc[mt][0] = MFMA16(af[mt][0], bl[0], acc[mt][0]);
      acc[mt][0] = MFMA16(af[mt][1], bl[1], acc[mt][0]);
    }
    __builtin_amdgcn_s_setprio(0);
    SBAR();
    // ---- phase 2: read B nt1; stage A0(t+2) ----
    #pragma unroll
    for (int ks=0;ks<2;ks++)
      bh[ks] = *(const s16x8*)(SB + (((wn*2+1)*2+ks)<<9) + baseF);
    ST_A0(bs, t+2);
    SBAR(); LGKM0();
    __builtin_amdgcn_s_setprio(1);
    #pragma unroll
    for (int mt=0;mt<4;mt++){
      acc[mt][1] = MFMA16(af[mt][0], bh[0], acc[mt][1]);
      acc[mt][1] = MFMA16(af[mt][1], bh[1], acc[mt][1]);
    }
    __builtin_amdgcn_s_setprio(0);
    SBAR();
    // ---- phase 3: read A rows64-127; stage B(t+2) ----
    #pragma unroll
    for (int mt=0;mt<4;mt++)
      #pragma unroll
      for (int ks=0;ks<2;ks++)
        af[mt][ks] = *(const s16x8*)(SA + (((4+mt)*2+ks)<<9) + baseF);
    ST_B(bs, t+2);
    SBAR(); LGKM0();
    __builtin_amdgcn_s_setprio(1);
    #pragma unroll
    for (int mt=0;mt<4;mt++){
      acc[4+mt][0] = MFMA16(af[mt][0], bl[0], acc[4+mt][0]);
      acc[4+mt][0] = MFMA16(af[mt][1], bl[1], acc[4+mt][0]);
    }
    __builtin_amdgcn_s_setprio(0);
    SBAR();
    // ---- phase 4 ----
    __builtin_amdgcn_s_setprio(1);
    #pragma unroll
    for (int mt=0;mt<4;mt++){
      acc[4+mt][1] = MFMA16(af[mt][0], bh[0], acc[4+mt][1]);
      acc[4+mt][1] = MFMA16(af[mt][1], bh[1], acc[4+mt][1]);
    }
    __builtin_amdgcn_s_setprio(0);
    VMC4();
    SBAR();
  }
#undef ST_A0
#undef ST_A1
#undef ST_B

  const long Rb = tileM + wm*128 + quad*4;
  const long Cb = tileN + wn*32 + fr;
  if (BF16_OUT){
    ushort* C = (ushort*)Cv;
    #pragma unroll
    for (int mt=0;mt<8;mt++)
      #pragma unroll
      for (int r=0;r<4;r++){
        const long row = Rb + mt*16 + r;
        #pragma unroll
        for (int nt=0;nt<2;nt++)
          C[row*(long)N + Cb + nt*16] = f2bf(acc[mt][nt][r]);
      }
  } else {
    float* C = (float*)Cv;
    #pragma unroll
    for (int mt=0;mt<8;mt++)
      #pragma unroll
      for (int r=0;r<4;r++){
        const long row = Rb + mt*16 + r;
        #pragma unroll
        for (int nt=0;nt<2;nt++)
          C[row*(long)N + Cb + nt*16] = acc[mt][nt][r];
      }
  }
}

// ------- split-K GEMM for ba projection: C[4096,128] = hs[4096,2048] * Wba[128,2048]^T ----
// grid 256: mt = bid>>3 (M-tile 0..31), ks = bid&7 (K-slice of 256). Partial f32 out
// to Cp + ks*524288; ba_post2 sums the 8 slices.
__global__ __launch_bounds__(256, 2) void gemm_ba(const ushort* __restrict__ A,
                                                  const ushort* __restrict__ B,
                                                  float* __restrict__ Cp){
  __shared__ ushort As[128*32];
  __shared__ ushort Bs[128*32];
  const int mt0 = blockIdx.x>>3, ks = blockIdx.x&7;
  const int tile_m = mt0<<7;
  const int tid  = threadIdx.x;
  const int w    = tid >> 6;
  const int lane = tid & 63;
  const int K = 2048;

  const int ca = w*2;
  const long rowA = tile_m + ca*16 + (lane>>2);
  const long rowB = ca*16 + (lane>>2);
  const int  colE = (lane&3)*8 + ks*256;
  const ushort* pA0 = A + rowA*(long)K + colE;
  const ushort* pA1 = pA0 + 16l*K;
  const ushort* pB0 = B + rowB*(long)K + colE;
  const ushort* pB1 = pB0 + 16l*K;
  ushort* lA0 = As + ca*512;
  ushort* lA1 = As + ca*512 + 512;
  ushort* lB0 = Bs + ca*512;
  ushort* lB1 = Bs + ca*512 + 512;

  const int wr = (w>>1)<<6;
  const int wc = (w&1)<<6;
  const int fr = lane & 15;
  const int fk = (lane>>4)<<3;

  f32x4 acc[4][4];
  #pragma unroll
  for (int i=0;i<4;i++)
    #pragma unroll
    for (int j=0;j<4;j++) acc[i][j] = (f32x4){0.f,0.f,0.f,0.f};

  for (int k0 = 0; k0 < 256; k0 += 32){
    __syncthreads();
    gl_lds16(pA0, lA0);
    gl_lds16(pA1, lA1);
    gl_lds16(pB0, lB0);
    gl_lds16(pB1, lB1);
    __syncthreads();
    s16x8 af[4], bfr[4];
    #pragma unroll
    for (int t=0;t<4;t++){
      af[t]  = *(const s16x8*)(As + (wr + t*16 + fr)*32 + fk);
      bfr[t] = *(const s16x8*)(Bs + (wc + t*16 + fr)*32 + fk);
    }
    #pragma unroll
    for (int mt=0;mt<4;mt++)
      #pragma unroll
      for (int nt=0;nt<4;nt++)
        acc[mt][nt] = MFMA16(af[mt], bfr[nt], acc[mt][nt]);
    pA0 += 32; pA1 += 32; pB0 += 32; pB1 += 32;
  }

  float* C = Cp + (long)ks*524288;          // 4096*128 per slice
  const int crow = tile_m + wr + ((lane>>4)<<2);
  const int ccol = wc + (lane&15);
  #pragma unroll
  for (int mt=0;mt<4;mt++)
    #pragma unroll
    for (int r=0;r<4;r++){
      long row = crow + mt*16 + r;
      #pragma unroll
      for (int nt=0;nt<4;nt++)
        C[row*128 + ccol + nt*16] = acc[mt][nt][r];
    }
}

// ---------------- beta / log-decay epilogue, sums 8 K-slices ----------------
__global__ __launch_bounds__(256) void ba_post2(const float* __restrict__ bp,
    const float* __restrict__ dtb, const float* __restrict__ alog,
    float* __restrict__ beta, float* __restrict__ glog){
  const int idx = blockIdx.x*256 + threadIdx.x;     // over 4096*64
  const int m = idx >> 6, j = idx & 63;
  float v = 0.f;
  #pragma unroll
  for (int s=0;s<8;s++) v += bp[(long)s*524288 + (long)m*128 + j];
  if (j < 32){
    beta[(long)m*32 + j] = 1.f/(1.f+expf(-v));
  } else {
    const int n = j - 32;
    float ap = v + dtb[n];
    float sp = (ap > 20.f) ? ap : log1pf(expf(ap));
    glog[(long)m*32 + n] = -expf(alog[n]) * sp;     // log decay g
  }
}

// ------- causal depthwise conv(K=4) + silu + l2norm(q,k), register sliding window -------
__global__ __launch_bounds__(256) void conv_qkv2(const ushort* __restrict__ mixed,
    const float* __restrict__ convw, ushort* __restrict__ qn, ushort* __restrict__ kn,
    ushort* __restrict__ vv){
  const long m0 = (long)blockIdx.x * 32;
  const int ct = blockIdx.y;
  const int ch = (ct<<11) + threadIdx.x*8;
  const ushort* base = mixed + ch;

  ushort* outp; int mode; float qsc = 1.f;
  if (ct == 0){ outp = qn + ch;        mode = 0; qsc = 0.08838834764831845f; }
  else if (ct == 1){ outp = kn + (ch-2048); mode = 1; }
  else { outp = vv + (ch-4096); mode = 2; }

  float cw0[8], cw1[8], cw2[8], cw3[8];
  #pragma unroll
  for (int e=0;e<8;e++){
    float4 wv = *(const float4*)(convw + (long)(ch+e)*4);
    cw0[e]=wv.x; cw1[e]=wv.y; cw2[e]=wv.z; cw3[e]=wv.w;
  }

#define LDROW(PTR, R) do{ s16x8 _v = *(const s16x8*)(PTR); \
    _Pragma("unroll") \
    for (int e=0;e<8;e++) R[e] = bf2f((ushort)_v[e]); }while(0)

#define STEP(P0,P1,P2,P3,MR) do{ \
    float y[8]; float ss = 0.f; \
    _Pragma("unroll") \
    for (int e=0;e<8;e++){ \
      float a = P0[e]*cw0[e]; \
      a += P1[e]*cw1[e]; \
      a += P2[e]*cw2[e]; \
      a += P3[e]*cw3[e]; \
      float sv = a / (1.f + expf(-a)); \
      y[e] = sv; ss += sv*sv; } \
    if (mode < 2){ \
      ss += __shfl_xor(ss,1); ss += __shfl_xor(ss,2); \
      ss += __shfl_xor(ss,4); ss += __shfl_xor(ss,8); \
      const float r_ = rsqrtf(ss + 1e-6f) * qsc; \
      s16x8 ov; \
      _Pragma("unroll") \
      for (int e=0;e<8;e++) ov[e] = (short)f2bf(y[e]*r_); \
      *(s16x8*)(outp + (MR)*2048) = ov; \
    } else { \
      s16x8 ov; \
      _Pragma("unroll") \
      for (int e=0;e<8;e++) ov[e] = (short)f2bf(y[e]); \
      *(s16x8*)(outp + (MR)*4096) = ov; \
    } \
  }while(0)

  float w3[8], w2[8], w1[8];      // rows m-3, m-2, m-1
  if (((int)m0 & 2047) == 0){
    #pragma unroll
    for (int e=0;e<8;e++){ w3[e]=0.f; w2[e]=0.f; w1[e]=0.f; }
  } else {
    LDROW(base + (m0-3)*8192, w3);
    LDROW(base + (m0-2)*8192, w2);
    LDROW(base + (m0-1)*8192, w1);
  }

  long m = m0;
  for (int it=0; it<8; ++it){
    float r0[8], r1[8], r2[8], r3[8];
    LDROW(base + (m+0)*8192, r0);
    LDROW(base + (m+1)*8192, r1);
    LDROW(base + (m+2)*8192, r2);
    LDROW(base + (m+3)*8192, r3);
    STEP(w3,w2,w1,r0, m+0);
    STEP(w2,w1,r0,r1, m+1);
    STEP(w1,r0,r1,r2, m+2);
    STEP(r0,r1,r2,r3, m+3);
    #pragma unroll
    for (int e=0;e<8;e++){ w3[e]=r1[e]; w2[e]=r2[e]; w1[e]=r3[e]; }
    m += 4;
  }
#undef LDROW
#undef STEP
}

// ---------------- pass 1: per-chunk T=(I+Ahat)^-1, M, cumLg (parallel, 4096 blocks) --------
__global__ __launch_bounds__(256) void chunk_prep(
    const ushort* __restrict__ qn, const ushort* __restrict__ kn,
    const float* __restrict__ beta, const float* __restrict__ glog,
    ushort* __restrict__ Tg, ushort* __restrict__ Mg, float* __restrict__ cumLgG){
  const int bid = blockIdx.x;
  const int bh = bid >> 6, ch = bid & 63;
  const int b = bh>>5, h = bh&31, hq = h>>1;
  const long tch = (long)b*2048 + ch*32;
  const int tid = threadIdx.x, w = tid>>6, lane = tid&63;
  const int quad = lane>>4, l15 = lane&15;

  __shared__ __attribute__((aligned(16))) ushort Kl[32][136];
  __shared__ __attribute__((aligned(16))) ushort Ql[32][136];
  __shared__ float Asl[32][33];
  __shared__ float Lgl[32], Btl[32];

  const int sc = tid>>3, ss = (tid&7)*16;
  {
    const ushort* kp = kn + (tch+sc)*2048 + hq*128 + ss;
    const ushort* qp = qn + (tch+sc)*2048 + hq*128 + ss;
    *(u32x4*)&Kl[sc][ss] = *(const u32x4*)kp; *(u32x4*)&Kl[sc][ss+8] = *(const u32x4*)(kp+8);
    *(u32x4*)&Ql[sc][ss] = *(const u32x4*)qp; *(u32x4*)&Ql[sc][ss+8] = *(const u32x4*)(qp+8);
  }
  if (tid < 64){
    const int c = lane & 31;
    float gv = glog[(tch + c)*32 + h];
    float bv = beta[(tch + c)*32 + h];
    #pragma unroll
    for (int off=1; off<32; off<<=1){
      float t = __shfl_up(gv, off);
      if ((lane & 31) >= off) gv += t;
    }
    if (lane < 32){ Lgl[c] = gv; Btl[c] = bv; cumLgG[(long)bid*32 + c] = gv; }
  }
  __syncthreads();

  const int mt = w>>1, nt = w&1;
  s16x8 ka[4], qa[4], kb[4];
  #pragma unroll
  for (int ks=0; ks<4; ks++){
    ka[ks] = *(const s16x8*)&Kl[mt*16+l15][ks*32 + quad*8];
    qa[ks] = *(const s16x8*)&Ql[mt*16+l15][ks*32 + quad*8];
    kb[ks] = *(const s16x8*)&Kl[nt*16+l15][ks*32 + quad*8];
  }
  f32x4 accK = (f32x4){0.f,0.f,0.f,0.f}, accQ = (f32x4){0.f,0.f,0.f,0.f};
  #pragma unroll
  for (int ks=0; ks<4; ks++){
    accK = MFMA16(ka[ks], kb[ks], accK);
    accQ = MFMA16(qa[ks], kb[ks], accQ);
  }
  const int j = nt*16 + l15;
  const float Lgj = Lgl[j];
  #pragma unroll
  for (int i=0;i<4;i++){
    const int r = mt*16 + quad*4 + i;
    const float e = expf(Lgl[r]-Lgj);
    Asl[r][j] = (r>j) ? -Btl[r]*e*accK[i] : 0.f;   // = -Ahat
    Mg[(long)bid*1024 + r*32 + j] = (r>=j) ? f2bf(e*accQ[i]) : (ushort)0;
  }
  __syncthreads();

  if (tid < 32){
    const int jc = tid;
    float tc[32];
    #pragma unroll
    for (int c=0;c<32;c++){
      float acc = (c==jc) ? 1.f : 0.f;
      #pragma unroll
      for (int i2=0;i2<c;i2++) acc = fmaf(Asl[c][i2], tc[i2], acc);
      tc[c] = acc;
      Tg[(long)bid*1024 + c*32 + jc] = f2bf(acc);
    }
  }
}

// ---------------- pass 2: sequential inter-chunk recurrence, latency-optimized ----------------
__global__ __launch_bounds__(256, 2) void chunk_scan3(
    const ushort* __restrict__ qn, const ushort* __restrict__ kn,
    const ushort* __restrict__ vv, const float* __restrict__ beta,
    const float* __restrict__ cumLg, const ushort* __restrict__ Tg,
    const ushort* __restrict__ Mg, float* __restrict__ o){
  const int bh = blockIdx.x & 63, sl = blockIdx.x >> 6;
  const int b = bh>>5, h = bh&31, hq = h>>1;
  const int dv0 = sl<<4;
  const int tid = threadIdx.x, w = tid>>6, lane = tid&63;
  const int quad = lane>>4, l15 = lane&15;
  const int rt = w&1, kq = w>>1;

  __shared__ __attribute__((aligned(16))) ushort STl[16][136];  // S^T [dv][dk]
  __shared__ __attribute__((aligned(16))) ushort B0T[16][40];   // b0^T [dv][row]
  __shared__ __attribute__((aligned(16))) ushort DT[16][40];    // D   [dv][row]
  __shared__ float Btf[32], eLgl[32], eDf[32];

  const ushort* pKQ = (kq ? qn : kn) + ((long)b*2048 + rt*16 + l15)*2048 + hq*128 + quad*8;
  const ushort* pKT = kn + ((long)b*2048 + quad*8)*2048 + hq*128 + w*32 + l15;
  const ushort* pV  = vv + ((long)b*2048 + rt*16 + quad*4)*4096 + h*128 + dv0 + l15;
  const ushort* pTM = (kq ? Mg : Tg) + (long)bh*65536 + (rt*16 + l15)*32 + quad*8;
  const long pbBase = (long)bh*2048 + tid;
  const float* betaP = beta + ((long)b*2048 + tid)*32 + h;

  s16x8 cKQ[4], nKQ[4], cK0, cK1, nK0, nK1, cTM, nTM;
  ushort cV0=0,cV1=0,cV2=0,cV3=0, nV0=0,nV1=0,nV2=0,nV3=0;
  float cLg = 0.f, nLg = 0.f, cBt = 0.f, nBt = 0.f;

  f32x4 S0 = (f32x4){0.f,0.f,0.f,0.f}, S1 = (f32x4){0.f,0.f,0.f,0.f};

#define LOADCH(PKQ,PK0,PK1,PV0,PV1,PV2,PV3,PTMv,PLG,PBT,CH) do{ \
    const long co = (long)(CH)*65536; \
    _Pragma("unroll") \
    for (int ks=0; ks<4; ks++) PKQ[ks] = *(const s16x8*)(pKQ + co + ks*32); \
    _Pragma("unroll") \
    for (int e=0; e<8; e++){ \
      PK0[e] = (short)pKT[co + (long)e*2048]; \
      PK1[e] = (short)pKT[co + (long)e*2048 + 16]; } \
    if (kq == 0){ \
      const long vo = (long)(CH)*131072; \
      PV0 = pV[vo]; PV1 = pV[vo+4096]; PV2 = pV[vo+8192]; PV3 = pV[vo+12288]; } \
    PTMv = *(const s16x8*)(pTM + (long)(CH)*1024); \
    if (tid < 32){ PLG = cumLg[pbBase + (long)(CH)*32]; PBT = betaP[(long)(CH)*1024]; } \
  }while(0)

  LOADCH(cKQ, cK0, cK1, cV0,cV1,cV2,cV3, cTM, cLg, cBt, 0);

  for (int ch=0; ch<64; ch++){
    const long tch = (long)b*2048 + ch*32;
    LOADCH(nKQ, nK0, nK1, nV0,nV1,nV2,nV3, nTM, nLg, nBt, (ch<63)?(ch+1):63);
    if (tid < 32){
      float lgC = __shfl(cLg, 31);
      Btf[tid] = cBt;
      eLgl[tid] = expf(cLg);
      eDf[tid]  = expf(lgC - cLg);
    }
    {
      ushort4 p0, p1;
      p0.x=f2bf(S0[0]); p0.y=f2bf(S0[1]); p0.z=f2bf(S0[2]); p0.w=f2bf(S0[3]);
      p1.x=f2bf(S1[0]); p1.y=f2bf(S1[1]); p1.z=f2bf(S1[2]); p1.w=f2bf(S1[3]);
      *(ushort4*)&STl[l15][w*32 + quad*4]      = p0;
      *(ushort4*)&STl[l15][w*32 + 16 + quad*4] = p1;
    }
    __syncthreads();
    f32x4 acc = (f32x4){0.f,0.f,0.f,0.f};
    #pragma unroll
    for (int ks=0; ks<4; ks++){
      s16x8 sb = *(const s16x8*)&STl[l15][ks*32 + quad*8];
      acc = MFMA16(cKQ[ks], sb, acc);
    }
    if (kq == 0){
      const int c0r = rt*16 + quad*4;
      ushort4 pb;
      pb.x = f2bf(Btf[c0r+0]*(bf2f(cV0) - eLgl[c0r+0]*acc[0]));
      pb.y = f2bf(Btf[c0r+1]*(bf2f(cV1) - eLgl[c0r+1]*acc[1]));
      pb.z = f2bf(Btf[c0r+2]*(bf2f(cV2) - eLgl[c0r+2]*acc[2]));
      pb.w = f2bf(Btf[c0r+3]*(bf2f(cV3) - eLgl[c0r+3]*acc[3]));
      *(ushort4*)&B0T[l15][rt*16 + quad*4] = pb;
    } else {
      #pragma unroll
      for (int i=0;i<4;i++) acc[i] *= eLgl[rt*16 + quad*4 + i];
    }
    __syncthreads();
    const float eC = eLgl[31];
    s16x8 kta0, kta1;
    #pragma unroll
    for (int e=0;e<8;e++){
      const float ed = eDf[quad*8 + e];
      kta0[e] = (short)f2bf(bf2f((ushort)cK0[e])*ed);
      kta1[e] = (short)f2bf(bf2f((ushort)cK1[e])*ed);
    }
    if (kq == 0){
      s16x8 a = *(const s16x8*)&B0T[l15][quad*8];
      f32x4 Dt = MFMA16(a, cTM, ((f32x4){0.f,0.f,0.f,0.f}));
      #pragma unroll
      for (int i=0;i<4;i++)
        DT[quad*4+i][rt*16 + l15] = f2bf(Dt[i]);
    }
    __syncthreads();
    s16x8 df = *(const s16x8*)&DT[l15][quad*8];
    if (kq == 1){
      f32x4 O = MFMA16(cTM, df, acc);
      #pragma unroll
      for (int i=0;i<4;i++)
        o[(tch + rt*16 + quad*4 + i)*4096 + h*128 + dv0 + l15] = O[i];
    }
    f32x4 t0, t1;
    #pragma unroll
    for (int i=0;i<4;i++){ t0[i] = S0[i]*eC; t1[i] = S1[i]*eC; }
    S0 = MFMA16(kta0, df, t0);
    S1 = MFMA16(kta1, df, t1);
    #pragma unroll
    for (int ks=0; ks<4; ks++) cKQ[ks] = nKQ[ks];
    cK0 = nK0; cK1 = nK1; cTM = nTM;
    cV0 = nV0; cV1 = nV1; cV2 = nV2; cV3 = nV3;
    cLg = nLg; cBt = nBt;
  }
#undef LOADCH
}

// ---------------- RMSNorm(gated) + silu(z) gate, bf16 out — vectorized, no LDS ----------------
// grid 4096 x 256 thr: 32 lanes per row (float4/lane), 8 rows/pass, 4 passes.
__global__ __launch_bounds__(256) void norm_gate2(const float* __restrict__ o,
    const ushort* __restrict__ z, const float* __restrict__ normw,
    ushort* __restrict__ og){
  const int tid = threadIdx.x;
  const int rg = tid>>5, l = tid&31;
  const int d0 = l*4;
  const float4 nw = *(const float4*)(normw + d0);
  long row = (long)blockIdx.x*32 + rg;
  #pragma unroll
  for (int it=0; it<4; ++it){
    const float4 xv = *(const float4*)(o + row*128 + d0);
    const ushort4 zv = *(const ushort4*)(z + row*128 + d0);
    float ss = xv.x*xv.x + xv.y*xv.y + xv.z*xv.z + xv.w*xv.w;
    ss += __shfl_xor(ss,1); ss += __shfl_xor(ss,2); ss += __shfl_xor(ss,4);
    ss += __shfl_xor(ss,8); ss += __shfl_xor(ss,16);
    const float r = rsqrtf(ss*(1.f/128.f) + 1e-6f);
    ushort4 ov; float zz, sil;
    zz = bf2f(zv.x); sil = zz/(1.f+expf(-zz)); ov.x = f2bf(xv.x*r*nw.x*sil);
    zz = bf2f(zv.y); sil = zz/(1.f+expf(-zz)); ov.y = f2bf(xv.y*r*nw.y*sil);
    zz = bf2f(zv.z); sil = zz/(1.f+expf(-zz)); ov.z = f2bf(xv.z*r*nw.z*sil);
    zz = bf2f(zv.w); sil = zz/(1.f+expf(-zz)); ov.w = f2bf(xv.w*r*nw.w*sil);
    *(ushort4*)(og + row*128 + d0) = ov;
    row += 8;
  }
}

extern "C" void kernel_launch(void* const* d_in, const int* in_sizes, int n_in,
                              void* d_out, int out_size, void* d_ws, size_t ws_size,
                              hipStream_t stream){
  const float* hs    = (const float*)d_in[0];
  const float* Wqkv  = (const float*)d_in[1];
  const float* Wz    = (const float*)d_in[2];
  const float* Wb    = (const float*)d_in[3];
  const float* Wa    = (const float*)d_in[4];
  const float* convw = (const float*)d_in[5];
  const float* normw = (const float*)d_in[6];
  const float* Wout  = (const float*)d_in[7];
  const float* dtb   = (const float*)d_in[8];
  const float* alog  = (const float*)d_in[9];

  char* ws = (char*)d_ws;
  ushort* hsb   = (ushort*)(ws);                 // [0,16M)    hs bf16  -> later kn
  ushort* wqb   = (ushort*)(ws + (16l<<20));     // [16,48M)   Wqkv bf16 -> later v -> og
  ushort* wzb   = (ushort*)(ws + (48l<<20));     // [48,64M)   Wz bf16  -> later qn
  ushort* wob   = (ushort*)(ws + (64l<<20));     // [64,80M)   Wout bf16
  ushort* mixed = (ushort*)(ws + (80l<<20));     // [80,144M)  mixed bf16 -> later o_raw f32
  ushort* zb    = (ushort*)(ws + (144l<<20));    // [144,176M) z bf16
  float*  beta  = (float*)(ws + (176l<<20));     // 512K
  float*  cumLg = (float*)(ws + (176l<<20) + (512l<<10)); // 512K
  float*  glog  = (float*)(ws + (177l<<20));     // 512K
  ushort* Tg    = (ushort*)(ws + (178l<<20));    // [178,186M) T bf16 (also ba partials earlier)
  ushort* Mg    = (ushort*)(ws + (186l<<20));    // [186,194M) M bf16
  ushort* wbab  = (ushort*)(ws + (194l<<20));    // [194,194.5M) W_ba bf16 [128][2048]
  float*  bapr8 = (float*)(ws + (178l<<20));     // 8 x [4096][128] f32 = 16M, dead before chunk_prep
  ushort* kn = hsb;  ushort* qn = wzb;  ushort* vvp = wqb;  ushort* og = wqb;
  float*  o_raw = (float*)mixed;

  cvt_bf16<<<8192,  256, 0, stream>>>(hs,   hsb);
  cvt_bf16<<<16384, 256, 0, stream>>>(Wqkv, wqb);
  cvt_bf16<<<8192,  256, 0, stream>>>(Wz,   wzb);
  cvt_bf16<<<8192,  256, 0, stream>>>(Wout, wob);
  cvt_bf16<<<64,    256, 0, stream>>>(Wb,   wbab);          // rows 0..31
  cvt_bf16<<<64,    256, 0, stream>>>(Wa,   wbab + 65536);  // rows 32..63 (64..127 garbage, cols 64..127 of C unread)

  gemm256<1><<<512, 512, 0, stream>>>(hsb, wqb, (void*)mixed, 4096, 8192, 2048, 4, 16);
  gemm256<1><<<256, 512, 0, stream>>>(hsb, wzb, (void*)zb,    4096, 4096, 2048, 4, 8);
  gemm_ba<<<256, 256, 0, stream>>>(hsb, wbab, bapr8);
  ba_post2<<<1024, 256, 0, stream>>>(bapr8, dtb, alog, beta, glog);

  conv_qkv2<<<dim3(128,4), 256, 0, stream>>>(mixed, convw, qn, kn, vvp);
  chunk_prep<<<4096, 256, 0, stream>>>(qn, kn, beta, glog, Tg, Mg, cumLg);
  chunk_scan3<<<512, 256, 0, stream>>>(qn, kn, vvp, beta, cumLg, Tg, Mg, o_raw);
  norm_gate2<<<4096, 256, 0, stream>>>(o_raw, zb, normw, og);

  gemm256n128<0><<<256, 512, 0, stream>>>(og, wob, d_out, 4096, 2048, 4096, 4, 8);
}

// Round 8
// 653.434 us; speedup vs baseline: 1.0899x; 1.0033x over previous
//
#include <hip/hip_runtime.h>
#include <hip/hip_bf16.h>
#include <math.h>

#define DEVI __device__ __forceinline__

typedef __attribute__((ext_vector_type(4))) float f32x4;
typedef __attribute__((ext_vector_type(8))) short s16x8;
typedef __attribute__((ext_vector_type(4))) unsigned int u32x4;

DEVI float bf2f(ushort u){ union{unsigned int i; float f;} x; x.i = ((unsigned int)u)<<16; return x.f; }
DEVI ushort f2bf(float f){ union{float f; unsigned int i;} x; x.f = f;
  unsigned int r = x.i + 0x7fffu + ((x.i>>16)&1u); return (ushort)(r>>16); }

#define MFMA16(a,b,c) __builtin_amdgcn_mfma_f32_16x16x32_bf16(a,b,c,0,0,0)

// ---------------- fp32 -> bf16 convert, 4 elems/thread ----------------
__global__ __launch_bounds__(256) void cvt_bf16(const float* __restrict__ in, ushort* __restrict__ out){
  int i = blockIdx.x*256 + threadIdx.x;
  float4 v = ((const float4*)in)[i];
  ushort4 o; o.x = f2bf(v.x); o.y = f2bf(v.y); o.z = f2bf(v.z); o.w = f2bf(v.w);
  ((ushort4*)out)[i] = o;
}

DEVI void gl_lds16(const ushort* g, ushort* l){
  __builtin_amdgcn_global_load_lds((const __attribute__((address_space(1))) void*)g,
                                   (__attribute__((address_space(3))) void*)l, 16, 0, 0);
}

#define SBAR() __builtin_amdgcn_s_barrier()
#define LGKM0() do{ asm volatile("s_waitcnt lgkmcnt(0)" ::: "memory"); __builtin_amdgcn_sched_barrier(0); }while(0)
#define VMC0() asm volatile("s_waitcnt vmcnt(0)" ::: "memory")
#define VMC4() asm volatile("s_waitcnt vmcnt(4)" ::: "memory")

// ============ 256x256-tile GEMM: single-region K-loop, 1 barrier per K-tile ============
// C[M,N] = A[M,K]*B[N,K]^T. 8 waves (2Mx4N), BK=64, double-buffered LDS (subtile swizzle).
// Per K-tile: {24 ds_read -> frags (ks0 group first); stage(t+1)->buf^1; 64 MFMA with
// compiler-counted lgkmcnt so LDS reads stream concurrently with MFMA; vmcnt(0); s_barrier}.
// Stage is 1 tile ahead (~2500 cyc cover >> 900 cyc HBM latency).
// XCD-region swizzle: XCD covers rpx tile-rows x cpx tile-cols, col-major walk.
template<int BF16_OUT>
__global__ __launch_bounds__(512, 2) void gemm256(const ushort* __restrict__ A,
                                                  const ushort* __restrict__ B,
                                                  void* __restrict__ Cv,
                                                  int M, int N, int K,
                                                  int rpx, int cpx){
  __shared__ ushort smem[65536];   // [buf2][slot4: A-lo,A-hi,B-lo,B-hi][8192]
  const int tid = threadIdx.x, w = tid>>6, lane = tid&63;
  const int fr = lane&15, quad = lane>>4;
  const int wm = w>>2, wn = w&3;
  const int NT = K>>6;

  const int nbn = N>>8;
  const int bid = blockIdx.x;
  const int xcd = bid & 7, idx = bid >> 3;
  const int CGn = nbn / cpx;
  const int rgrp = xcd / CGn, cgrp = xcd % CGn;
  const int rloc = idx % rpx, cloc = idx / rpx;
  const long tileM = (long)(rgrp*rpx + rloc) << 8;
  const long tileN = (long)(cgrp*cpx + cloc) << 8;

  const int rr  = (tid&63)>>2;                       // 0..15
  const int cc  = ((tid&3)*8) ^ ((rr&8)?16:0);
  const int row0 = (w>>1)*16 + rr;                   // rows 0..63
  const int col0 = (w&1)*32 + cc;
  const long off0 = (long)row0*K + col0;
  const long h64 = 64l*K;

  const ushort* pA0 = A + tileM*K + off0;
  const ushort* pA1 = pA0 + 128l*K;
  const ushort* pB0 = B + tileN*K + off0;
  const ushort* pB1 = pB0 + 128l*K;

  const int dw = w*512;

#define STG(bb,tt) do{ if((tt)<NT){ const long kk=(long)(tt)<<6; \
    gl_lds16(pA0+kk,     smem+(bb)*32768+dw); \
    gl_lds16(pA0+kk+h64, smem+(bb)*32768+4096+dw); \
    gl_lds16(pA1+kk,     smem+(bb)*32768+8192+dw); \
    gl_lds16(pA1+kk+h64, smem+(bb)*32768+12288+dw); \
    gl_lds16(pB0+kk,     smem+(bb)*32768+16384+dw); \
    gl_lds16(pB0+kk+h64, smem+(bb)*32768+20480+dw); \
    gl_lds16(pB1+kk,     smem+(bb)*32768+24576+dw); \
    gl_lds16(pB1+kk+h64, smem+(bb)*32768+28672+dw); } }while(0)

  const int baseF = fr*32 + ((quad*8) ^ ((fr&8)?16:0));
  const int sB = (wn&1)*4;

  f32x4 acc[8][4];
  #pragma unroll
  for (int i=0;i<8;i++)
    #pragma unroll
    for (int j=0;j<4;j++) acc[i][j] = (f32x4){0.f,0.f,0.f,0.f};

  STG(0,0);
  VMC0();
  SBAR();
  __builtin_amdgcn_sched_barrier(0);

  for (int t=0; t<NT; ++t){
    const int bs = t&1;
    const ushort* SA = smem + bs*32768 + wm*8192;
    const ushort* SB = smem + bs*32768 + 16384 + (wn>>1)*8192;
    s16x8 af[8][2], bf[4][2];
    // reads: ks0 group first so early MFMAs depend only on early reads
    #pragma unroll
    for (int nt=0;nt<4;nt++) bf[nt][0] = *(const s16x8*)(SB + (((sB+nt)*2+0)<<9) + baseF);
    #pragma unroll
    for (int mt=0;mt<8;mt++) af[mt][0] = *(const s16x8*)(SA + ((mt*2+0)<<9) + baseF);
    #pragma unroll
    for (int nt=0;nt<4;nt++) bf[nt][1] = *(const s16x8*)(SB + (((sB+nt)*2+1)<<9) + baseF);
    #pragma unroll
    for (int mt=0;mt<8;mt++) af[mt][1] = *(const s16x8*)(SA + ((mt*2+1)<<9) + baseF);
    STG(bs^1, t+1);                 // 1 tile ahead into the other buffer (WAR-safe)
    __builtin_amdgcn_s_setprio(1);
    #pragma unroll
    for (int ks=0;ks<2;ks++)
      #pragma unroll
      for (int mt=0;mt<8;mt++)
        #pragma unroll
        for (int nt=0;nt<4;nt++)
          acc[mt][nt] = MFMA16(af[mt][ks], bf[nt][ks], acc[mt][nt]);
    __builtin_amdgcn_s_setprio(0);
    VMC0();                         // stage(t+1) landed (issued ~full tile ago)
    SBAR();
    __builtin_amdgcn_sched_barrier(0);
  }
#undef STG

  const long Rb = tileM + wm*128 + quad*4;
  const long Cb = tileN + wn*64 + fr;
  if (BF16_OUT){
    ushort* C = (ushort*)Cv;
    #pragma unroll
    for (int mt=0;mt<8;mt++)
      #pragma unroll
      for (int r=0;r<4;r++){
        const long row = Rb + mt*16 + r;
        #pragma unroll
        for (int nt=0;nt<4;nt++)
          C[row*(long)N + Cb + nt*16] = f2bf(acc[mt][nt][r]);
      }
  } else {
    float* C = (float*)Cv;
    #pragma unroll
    for (int mt=0;mt<8;mt++)
      #pragma unroll
      for (int r=0;r<4;r++){
        const long row = Rb + mt*16 + r;
        #pragma unroll
        for (int nt=0;nt<4;nt++)
          C[row*(long)N + Cb + nt*16] = acc[mt][nt][r];
      }
  }
}

// ============ 256x128-tile 8-phase GEMM (for N=2048 out-proj) ============
template<int BF16_OUT>
__global__ __launch_bounds__(512, 2) void gemm256n128(const ushort* __restrict__ A,
                                                      const ushort* __restrict__ B,
                                                      void* __restrict__ Cv,
                                                      int M, int N, int K,
                                                      int rpx, int cpx){
  __shared__ ushort smem[49152];   // [buf2][A0,A1,B][8192]
  __shared__ ushort dummy[4096];
  const int tid = threadIdx.x, w = tid>>6, lane = tid&63;
  const int fr = lane&15, quad = lane>>4;
  const int wm = w>>2, wn = w&3;
  const int NT = K>>6;

  const int nbn = N>>7;
  const int bid = blockIdx.x;
  const int xcd = bid & 7, idx = bid >> 3;
  const int CGn = nbn / cpx;
  const int rgrp = xcd / CGn, cgrp = xcd % CGn;
  const int rloc = idx % rpx, cloc = idx / rpx;
  const long tileM = (long)(rgrp*rpx + rloc) << 8;
  const long tileN = (long)(cgrp*cpx + cloc) << 7;

  const int rr  = (tid&63)>>2;
  const int cc  = ((tid&3)*8) ^ ((rr&8)?16:0);
  const int row0 = (w>>1)*16 + rr;                   // rows 0..63
  const int col0 = (w&1)*32 + cc;
  const long off0 = (long)row0*K + col0;
  const long h64 = 64l*K;

  const ushort* pA0 = A + tileM*K + off0;
  const ushort* pA1 = pA0 + 128l*K;
  const ushort* pB0 = B + tileN*K + off0;

  const int dw = w*512;
  ushort* dmy = dummy + dw;

#define ST_A0(bb,tt) do{ if((tt)<NT){ const long kk=(long)(tt)<<6; \
    gl_lds16(pA0+kk, smem+(bb)*24576+dw);        gl_lds16(pA1+kk, smem+(bb)*24576+8192+dw);} \
    else { gl_lds16(pA0, dmy); gl_lds16(pA1, dmy);} }while(0)
#define ST_A1(bb,tt) do{ if((tt)<NT){ const long kk=((long)(tt)<<6)+h64; \
    gl_lds16(pA0+kk, smem+(bb)*24576+4096+dw);   gl_lds16(pA1+kk, smem+(bb)*24576+12288+dw);} \
    else { gl_lds16(pA0, dmy); gl_lds16(pA1, dmy);} }while(0)
#define ST_B(bb,tt) do{ if((tt)<NT){ const long kk=(long)(tt)<<6; \
    gl_lds16(pB0+kk, smem+(bb)*24576+16384+dw);  gl_lds16(pB0+kk+h64, smem+(bb)*24576+20480+dw);} \
    else { gl_lds16(pB0, dmy); gl_lds16(pB0, dmy);} }while(0)

  const int baseF = fr*32 + ((quad*8) ^ ((fr&8)?16:0));

  f32x4 acc[8][2];
  #pragma unroll
  for (int i=0;i<8;i++)
    #pragma unroll
    for (int j=0;j<2;j++) acc[i][j] = (f32x4){0.f,0.f,0.f,0.f};

  ST_A0(0,0); ST_B(0,0); ST_A1(0,0);
  ST_A0(1,1); ST_B(1,1);
  VMC4();
  SBAR();

  #pragma unroll 2
  for (int t=0; t<NT; ++t){
    const int bs = t&1;
    const ushort* SA = smem + bs*24576 + wm*8192;
    const ushort* SB = smem + bs*24576 + 16384;
    s16x8 af[4][2], bl[2], bh[2];
    // ---- phase 1: read A rows0-63 + B nt0; stage A1(t+1) ----
    #pragma unroll
    for (int mt=0;mt<4;mt++)
      #pragma unroll
      for (int ks=0;ks<2;ks++)
        af[mt][ks] = *(const s16x8*)(SA + ((mt*2+ks)<<9) + baseF);
    #pragma unroll
    for (int ks=0;ks<2;ks++)
      bl[ks] = *(const s16x8*)(SB + (((wn*2+0)*2+ks)<<9) + baseF);
    ST_A1(bs^1, t+1);
    SBAR(); LGKM0();
    __builtin_amdgcn_s_setprio(1);
    #pragma unroll
    for (int mt=0;mt<4;mt++){
      acc[mt][0] = MFMA16(af[mt][0], bl[0], acc[mt][0]);
      acc[mt][0] = MFMA16(af[mt][1], bl[1], acc[mt][0]);
    }
    __builtin_amdgcn_s_setprio(0);
    SBAR();
    // ---- phase 2: read B nt1; stage A0(t+2) ----
    #pragma unroll
    for (int ks=0;ks<2;ks++)
      bh[ks] = *(const s16x8*)(SB + (((wn*2+1)*2+ks)<<9) + baseF);
    ST_A0(bs, t+2);
    SBAR(); LGKM0();
    __builtin_amdgcn_s_setprio(1);
    #pragma unroll
    for (int mt=0;mt<4;mt++){
      acc[mt][1] = MFMA16(af[mt][0], bh[0], acc[mt][1]);
      acc[mt][1] = MFMA16(af[mt][1], bh[1], acc[mt][1]);
    }
    __builtin_amdgcn_s_setprio(0);
    SBAR();
    // ---- phase 3: read A rows64-127; stage B(t+2) ----
    #pragma unroll
    for (int mt=0;mt<4;mt++)
      #pragma unroll
      for (int ks=0;ks<2;ks++)
        af[mt][ks] = *(const s16x8*)(SA + (((4+mt)*2+ks)<<9) + baseF);
    ST_B(bs, t+2);
    SBAR(); LGKM0();
    __builtin_amdgcn_s_setprio(1);
    #pragma unroll
    for (int mt=0;mt<4;mt++){
      acc[4+mt][0] = MFMA16(af[mt][0], bl[0], acc[4+mt][0]);
      acc[4+mt][0] = MFMA16(af[mt][1], bl[1], acc[4+mt][0]);
    }
    __builtin_amdgcn_s_setprio(0);
    SBAR();
    // ---- phase 4 ----
    __builtin_amdgcn_s_setprio(1);
    #pragma unroll
    for (int mt=0;mt<4;mt++){
      acc[4+mt][1] = MFMA16(af[mt][0], bh[0], acc[4+mt][1]);
      acc[4+mt][1] = MFMA16(af[mt][1], bh[1], acc[4+mt][1]);
    }
    __builtin_amdgcn_s_setprio(0);
    VMC4();
    SBAR();
  }
#undef ST_A0
#undef ST_A1
#undef ST_B

  const long Rb = tileM + wm*128 + quad*4;
  const long Cb = tileN + wn*32 + fr;
  if (BF16_OUT){
    ushort* C = (ushort*)Cv;
    #pragma unroll
    for (int mt=0;mt<8;mt++)
      #pragma unroll
      for (int r=0;r<4;r++){
        const long row = Rb + mt*16 + r;
        #pragma unroll
        for (int nt=0;nt<2;nt++)
          C[row*(long)N + Cb + nt*16] = f2bf(acc[mt][nt][r]);
      }
  } else {
    float* C = (float*)Cv;
    #pragma unroll
    for (int mt=0;mt<8;mt++)
      #pragma unroll
      for (int r=0;r<4;r++){
        const long row = Rb + mt*16 + r;
        #pragma unroll
        for (int nt=0;nt<2;nt++)
          C[row*(long)N + Cb + nt*16] = acc[mt][nt][r];
      }
  }
}

// ------- split-K GEMM for ba projection: C[4096,128] = hs[4096,2048] * Wba[128,2048]^T ----
__global__ __launch_bounds__(256, 2) void gemm_ba(const ushort* __restrict__ A,
                                                  const ushort* __restrict__ B,
                                                  float* __restrict__ Cp){
  __shared__ ushort As[128*32];
  __shared__ ushort Bs[128*32];
  const int mt0 = blockIdx.x>>3, ks = blockIdx.x&7;
  const int tile_m = mt0<<7;
  const int tid  = threadIdx.x;
  const int w    = tid >> 6;
  const int lane = tid & 63;
  const int K = 2048;

  const int ca = w*2;
  const long rowA = tile_m + ca*16 + (lane>>2);
  const long rowB = ca*16 + (lane>>2);
  const int  colE = (lane&3)*8 + ks*256;
  const ushort* pA0 = A + rowA*(long)K + colE;
  const ushort* pA1 = pA0 + 16l*K;
  const ushort* pB0 = B + rowB*(long)K + colE;
  const ushort* pB1 = pB0 + 16l*K;
  ushort* lA0 = As + ca*512;
  ushort* lA1 = As + ca*512 + 512;
  ushort* lB0 = Bs + ca*512;
  ushort* lB1 = Bs + ca*512 + 512;

  const int wr = (w>>1)<<6;
  const int wc = (w&1)<<6;
  const int fr = lane & 15;
  const int fk = (lane>>4)<<3;

  f32x4 acc[4][4];
  #pragma unroll
  for (int i=0;i<4;i++)
    #pragma unroll
    for (int j=0;j<4;j++) acc[i][j] = (f32x4){0.f,0.f,0.f,0.f};

  for (int k0 = 0; k0 < 256; k0 += 32){
    __syncthreads();
    gl_lds16(pA0, lA0);
    gl_lds16(pA1, lA1);
    gl_lds16(pB0, lB0);
    gl_lds16(pB1, lB1);
    __syncthreads();
    s16x8 af[4], bfr[4];
    #pragma unroll
    for (int t=0;t<4;t++){
      af[t]  = *(const s16x8*)(As + (wr + t*16 + fr)*32 + fk);
      bfr[t] = *(const s16x8*)(Bs + (wc + t*16 + fr)*32 + fk);
    }
    #pragma unroll
    for (int mt=0;mt<4;mt++)
      #pragma unroll
      for (int nt=0;nt<4;nt++)
        acc[mt][nt] = MFMA16(af[mt], bfr[nt], acc[mt][nt]);
    pA0 += 32; pA1 += 32; pB0 += 32; pB1 += 32;
  }

  float* C = Cp + (long)ks*524288;          // 4096*128 per slice
  const int crow = tile_m + wr + ((lane>>4)<<2);
  const int ccol = wc + (lane&15);
  #pragma unroll
  for (int mt=0;mt<4;mt++)
    #pragma unroll
    for (int r=0;r<4;r++){
      long row = crow + mt*16 + r;
      #pragma unroll
      for (int nt=0;nt<4;nt++)
        C[row*128 + ccol + nt*16] = acc[mt][nt][r];
    }
}

// ---------------- beta / log-decay epilogue, sums 8 K-slices ----------------
__global__ __launch_bounds__(256) void ba_post2(const float* __restrict__ bp,
    const float* __restrict__ dtb, const float* __restrict__ alog,
    float* __restrict__ beta, float* __restrict__ glog){
  const int idx = blockIdx.x*256 + threadIdx.x;     // over 4096*64
  const int m = idx >> 6, j = idx & 63;
  float v = 0.f;
  #pragma unroll
  for (int s=0;s<8;s++) v += bp[(long)s*524288 + (long)m*128 + j];
  if (j < 32){
    beta[(long)m*32 + j] = 1.f/(1.f+expf(-v));
  } else {
    const int n = j - 32;
    float ap = v + dtb[n];
    float sp = (ap > 20.f) ? ap : log1pf(expf(ap));
    glog[(long)m*32 + n] = -expf(alog[n]) * sp;     // log decay g
  }
}

// ------- causal depthwise conv(K=4) + silu + l2norm(q,k), register sliding window -------
__global__ __launch_bounds__(256) void conv_qkv2(const ushort* __restrict__ mixed,
    const float* __restrict__ convw, ushort* __restrict__ qn, ushort* __restrict__ kn,
    ushort* __restrict__ vv){
  const long m0 = (long)blockIdx.x * 32;
  const int ct = blockIdx.y;
  const int ch = (ct<<11) + threadIdx.x*8;
  const ushort* base = mixed + ch;

  ushort* outp; int mode; float qsc = 1.f;
  if (ct == 0){ outp = qn + ch;        mode = 0; qsc = 0.08838834764831845f; }
  else if (ct == 1){ outp = kn + (ch-2048); mode = 1; }
  else { outp = vv + (ch-4096); mode = 2; }

  float cw0[8], cw1[8], cw2[8], cw3[8];
  #pragma unroll
  for (int e=0;e<8;e++){
    float4 wv = *(const float4*)(convw + (long)(ch+e)*4);
    cw0[e]=wv.x; cw1[e]=wv.y; cw2[e]=wv.z; cw3[e]=wv.w;
  }

#define LDROW(PTR, R) do{ s16x8 _v = *(const s16x8*)(PTR); \
    _Pragma("unroll") \
    for (int e=0;e<8;e++) R[e] = bf2f((ushort)_v[e]); }while(0)

#define STEP(P0,P1,P2,P3,MR) do{ \
    float y[8]; float ss = 0.f; \
    _Pragma("unroll") \
    for (int e=0;e<8;e++){ \
      float a = P0[e]*cw0[e]; \
      a += P1[e]*cw1[e]; \
      a += P2[e]*cw2[e]; \
      a += P3[e]*cw3[e]; \
      float sv = a / (1.f + expf(-a)); \
      y[e] = sv; ss += sv*sv; } \
    if (mode < 2){ \
      ss += __shfl_xor(ss,1); ss += __shfl_xor(ss,2); \
      ss += __shfl_xor(ss,4); ss += __shfl_xor(ss,8); \
      const float r_ = rsqrtf(ss + 1e-6f) * qsc; \
      s16x8 ov; \
      _Pragma("unroll") \
      for (int e=0;e<8;e++) ov[e] = (short)f2bf(y[e]*r_); \
      *(s16x8*)(outp + (MR)*2048) = ov; \
    } else { \
      s16x8 ov; \
      _Pragma("unroll") \
      for (int e=0;e<8;e++) ov[e] = (short)f2bf(y[e]); \
      *(s16x8*)(outp + (MR)*4096) = ov; \
    } \
  }while(0)

  float w3[8], w2[8], w1[8];      // rows m-3, m-2, m-1
  if (((int)m0 & 2047) == 0){
    #pragma unroll
    for (int e=0;e<8;e++){ w3[e]=0.f; w2[e]=0.f; w1[e]=0.f; }
  } else {
    LDROW(base + (m0-3)*8192, w3);
    LDROW(base + (m0-2)*8192, w2);
    LDROW(base + (m0-1)*8192, w1);
  }

  long m = m0;
  for (int it=0; it<8; ++it){
    float r0[8], r1[8], r2[8], r3[8];
    LDROW(base + (m+0)*8192, r0);
    LDROW(base + (m+1)*8192, r1);
    LDROW(base + (m+2)*8192, r2);
    LDROW(base + (m+3)*8192, r3);
    STEP(w3,w2,w1,r0, m+0);
    STEP(w2,w1,r0,r1, m+1);
    STEP(w1,r0,r1,r2, m+2);
    STEP(r0,r1,r2,r3, m+3);
    #pragma unroll
    for (int e=0;e<8;e++){ w3[e]=r1[e]; w2[e]=r2[e]; w1[e]=r3[e]; }
    m += 4;
  }
#undef LDROW
#undef STEP
}

// ---------------- pass 1: per-chunk T=(I+Ahat)^-1, M, cumLg (parallel, 4096 blocks) --------
__global__ __launch_bounds__(256) void chunk_prep(
    const ushort* __restrict__ qn, const ushort* __restrict__ kn,
    const float* __restrict__ beta, const float* __restrict__ glog,
    ushort* __restrict__ Tg, ushort* __restrict__ Mg, float* __restrict__ cumLgG){
  const int bid = blockIdx.x;
  const int bh = bid >> 6, ch = bid & 63;
  const int b = bh>>5, h = bh&31, hq = h>>1;
  const long tch = (long)b*2048 + ch*32;
  const int tid = threadIdx.x, w = tid>>6, lane = tid&63;
  const int quad = lane>>4, l15 = lane&15;

  __shared__ __attribute__((aligned(16))) ushort Kl[32][136];
  __shared__ __attribute__((aligned(16))) ushort Ql[32][136];
  __shared__ float Asl[32][33];
  __shared__ float Lgl[32], Btl[32];

  const int sc = tid>>3, ss = (tid&7)*16;
  {
    const ushort* kp = kn + (tch+sc)*2048 + hq*128 + ss;
    const ushort* qp = qn + (tch+sc)*2048 + hq*128 + ss;
    *(u32x4*)&Kl[sc][ss] = *(const u32x4*)kp; *(u32x4*)&Kl[sc][ss+8] = *(const u32x4*)(kp+8);
    *(u32x4*)&Ql[sc][ss] = *(const u32x4*)qp; *(u32x4*)&Ql[sc][ss+8] = *(const u32x4*)(qp+8);
  }
  if (tid < 64){
    const int c = lane & 31;
    float gv = glog[(tch + c)*32 + h];
    float bv = beta[(tch + c)*32 + h];
    #pragma unroll
    for (int off=1; off<32; off<<=1){
      float t = __shfl_up(gv, off);
      if ((lane & 31) >= off) gv += t;
    }
    if (lane < 32){ Lgl[c] = gv; Btl[c] = bv; cumLgG[(long)bid*32 + c] = gv; }
  }
  __syncthreads();

  const int mt = w>>1, nt = w&1;
  s16x8 ka[4], qa[4], kb[4];
  #pragma unroll
  for (int ks=0; ks<4; ks++){
    ka[ks] = *(const s16x8*)&Kl[mt*16+l15][ks*32 + quad*8];
    qa[ks] = *(const s16x8*)&Ql[mt*16+l15][ks*32 + quad*8];
    kb[ks] = *(const s16x8*)&Kl[nt*16+l15][ks*32 + quad*8];
  }
  f32x4 accK = (f32x4){0.f,0.f,0.f,0.f}, accQ = (f32x4){0.f,0.f,0.f,0.f};
  #pragma unroll
  for (int ks=0; ks<4; ks++){
    accK = MFMA16(ka[ks], kb[ks], accK);
    accQ = MFMA16(qa[ks], kb[ks], accQ);
  }
  const int j = nt*16 + l15;
  const float Lgj = Lgl[j];
  #pragma unroll
  for (int i=0;i<4;i++){
    const int r = mt*16 + quad*4 + i;
    const float e = expf(Lgl[r]-Lgj);
    Asl[r][j] = (r>j) ? -Btl[r]*e*accK[i] : 0.f;   // = -Ahat
    Mg[(long)bid*1024 + r*32 + j] = (r>=j) ? f2bf(e*accQ[i]) : (ushort)0;
  }
  __syncthreads();

  if (tid < 32){
    const int jc = tid;
    float tc[32];
    #pragma unroll
    for (int c=0;c<32;c++){
      float acc = (c==jc) ? 1.f : 0.f;
      #pragma unroll
      for (int i2=0;i2<c;i2++) acc = fmaf(Asl[c][i2], tc[i2], acc);
      tc[c] = acc;
      Tg[(long)bid*1024 + c*32 + jc] = f2bf(acc);
    }
  }
}

// ---------------- pass 2: sequential inter-chunk recurrence, latency-optimized ----------------
__global__ __launch_bounds__(256, 2) void chunk_scan3(
    const ushort* __restrict__ qn, const ushort* __restrict__ kn,
    const ushort* __restrict__ vv, const float* __restrict__ beta,
    const float* __restrict__ cumLg, const ushort* __restrict__ Tg,
    const ushort* __restrict__ Mg, float* __restrict__ o){
  const int bh = blockIdx.x & 63, sl = blockIdx.x >> 6;
  const int b = bh>>5, h = bh&31, hq = h>>1;
  const int dv0 = sl<<4;
  const int tid = threadIdx.x, w = tid>>6, lane = tid&63;
  const int quad = lane>>4, l15 = lane&15;
  const int rt = w&1, kq = w>>1;

  __shared__ __attribute__((aligned(16))) ushort STl[16][136];  // S^T [dv][dk]
  __shared__ __attribute__((aligned(16))) ushort B0T[16][40];   // b0^T [dv][row]
  __shared__ __attribute__((aligned(16))) ushort DT[16][40];    // D   [dv][row]
  __shared__ float Btf[32], eLgl[32], eDf[32];

  const ushort* pKQ = (kq ? qn : kn) + ((long)b*2048 + rt*16 + l15)*2048 + hq*128 + quad*8;
  const ushort* pKT = kn + ((long)b*2048 + quad*8)*2048 + hq*128 + w*32 + l15;
  const ushort* pV  = vv + ((long)b*2048 + rt*16 + quad*4)*4096 + h*128 + dv0 + l15;
  const ushort* pTM = (kq ? Mg : Tg) + (long)bh*65536 + (rt*16 + l15)*32 + quad*8;
  const long pbBase = (long)bh*2048 + tid;
  const float* betaP = beta + ((long)b*2048 + tid)*32 + h;

  s16x8 cKQ[4], nKQ[4], cK0, cK1, nK0, nK1, cTM, nTM;
  ushort cV0=0,cV1=0,cV2=0,cV3=0, nV0=0,nV1=0,nV2=0,nV3=0;
  float cLg = 0.f, nLg = 0.f, cBt = 0.f, nBt = 0.f;

  f32x4 S0 = (f32x4){0.f,0.f,0.f,0.f}, S1 = (f32x4){0.f,0.f,0.f,0.f};

#define LOADCH(PKQ,PK0,PK1,PV0,PV1,PV2,PV3,PTMv,PLG,PBT,CH) do{ \
    const long co = (long)(CH)*65536; \
    _Pragma("unroll") \
    for (int ks=0; ks<4; ks++) PKQ[ks] = *(const s16x8*)(pKQ + co + ks*32); \
    _Pragma("unroll") \
    for (int e=0; e<8; e++){ \
      PK0[e] = (short)pKT[co + (long)e*2048]; \
      PK1[e] = (short)pKT[co + (long)e*2048 + 16]; } \
    if (kq == 0){ \
      const long vo = (long)(CH)*131072; \
      PV0 = pV[vo]; PV1 = pV[vo+4096]; PV2 = pV[vo+8192]; PV3 = pV[vo+12288]; } \
    PTMv = *(const s16x8*)(pTM + (long)(CH)*1024); \
    if (tid < 32){ PLG = cumLg[pbBase + (long)(CH)*32]; PBT = betaP[(long)(CH)*1024]; } \
  }while(0)

  LOADCH(cKQ, cK0, cK1, cV0,cV1,cV2,cV3, cTM, cLg, cBt, 0);

  for (int ch=0; ch<64; ch++){
    const long tch = (long)b*2048 + ch*32;
    LOADCH(nKQ, nK0, nK1, nV0,nV1,nV2,nV3, nTM, nLg, nBt, (ch<63)?(ch+1):63);
    if (tid < 32){
      float lgC = __shfl(cLg, 31);
      Btf[tid] = cBt;
      eLgl[tid] = expf(cLg);
      eDf[tid]  = expf(lgC - cLg);
    }
    {
      ushort4 p0, p1;
      p0.x=f2bf(S0[0]); p0.y=f2bf(S0[1]); p0.z=f2bf(S0[2]); p0.w=f2bf(S0[3]);
      p1.x=f2bf(S1[0]); p1.y=f2bf(S1[1]); p1.z=f2bf(S1[2]); p1.w=f2bf(S1[3]);
      *(ushort4*)&STl[l15][w*32 + quad*4]      = p0;
      *(ushort4*)&STl[l15][w*32 + 16 + quad*4] = p1;
    }
    __syncthreads();
    f32x4 acc = (f32x4){0.f,0.f,0.f,0.f};
    #pragma unroll
    for (int ks=0; ks<4; ks++){
      s16x8 sb = *(const s16x8*)&STl[l15][ks*32 + quad*8];
      acc = MFMA16(cKQ[ks], sb, acc);
    }
    if (kq == 0){
      const int c0r = rt*16 + quad*4;
      ushort4 pb;
      pb.x = f2bf(Btf[c0r+0]*(bf2f(cV0) - eLgl[c0r+0]*acc[0]));
      pb.y = f2bf(Btf[c0r+1]*(bf2f(cV1) - eLgl[c0r+1]*acc[1]));
      pb.z = f2bf(Btf[c0r+2]*(bf2f(cV2) - eLgl[c0r+2]*acc[2]));
      pb.w = f2bf(Btf[c0r+3]*(bf2f(cV3) - eLgl[c0r+3]*acc[3]));
      *(ushort4*)&B0T[l15][rt*16 + quad*4] = pb;
    } else {
      #pragma unroll
      for (int i=0;i<4;i++) acc[i] *= eLgl[rt*16 + quad*4 + i];
    }
    __syncthreads();
    const float eC = eLgl[31];
    s16x8 kta0, kta1;
    #pragma unroll
    for (int e=0;e<8;e++){
      const float ed = eDf[quad*8 + e];
      kta0[e] = (short)f2bf(bf2f((ushort)cK0[e])*ed);
      kta1[e] = (short)f2bf(bf2f((ushort)cK1[e])*ed);
    }
    if (kq == 0){
      s16x8 a = *(const s16x8*)&B0T[l15][quad*8];
      f32x4 Dt = MFMA16(a, cTM, ((f32x4){0.f,0.f,0.f,0.f}));
      #pragma unroll
      for (int i=0;i<4;i++)
        DT[quad*4+i][rt*16 + l15] = f2bf(Dt[i]);
    }
    __syncthreads();
    s16x8 df = *(const s16x8*)&DT[l15][quad*8];
    if (kq == 1){
      f32x4 O = MFMA16(cTM, df, acc);
      #pragma unroll
      for (int i=0;i<4;i++)
        o[(tch + rt*16 + quad*4 + i)*4096 + h*128 + dv0 + l15] = O[i];
    }
    f32x4 t0, t1;
    #pragma unroll
    for (int i=0;i<4;i++){ t0[i] = S0[i]*eC; t1[i] = S1[i]*eC; }
    S0 = MFMA16(kta0, df, t0);
    S1 = MFMA16(kta1, df, t1);
    #pragma unroll
    for (int ks=0; ks<4; ks++) cKQ[ks] = nKQ[ks];
    cK0 = nK0; cK1 = nK1; cTM = nTM;
    cV0 = nV0; cV1 = nV1; cV2 = nV2; cV3 = nV3;
    cLg = nLg; cBt = nBt;
  }
#undef LOADCH
}

// ---------------- RMSNorm(gated) + silu(z) gate, bf16 out — vectorized, no LDS ----------------
__global__ __launch_bounds__(256) void norm_gate2(const float* __restrict__ o,
    const ushort* __restrict__ z, const float* __restrict__ normw,
    ushort* __restrict__ og){
  const int tid = threadIdx.x;
  const int rg = tid>>5, l = tid&31;
  const int d0 = l*4;
  const float4 nw = *(const float4*)(normw + d0);
  long row = (long)blockIdx.x*32 + rg;
  #pragma unroll
  for (int it=0; it<4; ++it){
    const float4 xv = *(const float4*)(o + row*128 + d0);
    const ushort4 zv = *(const ushort4*)(z + row*128 + d0);
    float ss = xv.x*xv.x + xv.y*xv.y + xv.z*xv.z + xv.w*xv.w;
    ss += __shfl_xor(ss,1); ss += __shfl_xor(ss,2); ss += __shfl_xor(ss,4);
    ss += __shfl_xor(ss,8); ss += __shfl_xor(ss,16);
    const float r = rsqrtf(ss*(1.f/128.f) + 1e-6f);
    ushort4 ov; float zz, sil;
    zz = bf2f(zv.x); sil = zz/(1.f+expf(-zz)); ov.x = f2bf(xv.x*r*nw.x*sil);
    zz = bf2f(zv.y); sil = zz/(1.f+expf(-zz)); ov.y = f2bf(xv.y*r*nw.y*sil);
    zz = bf2f(zv.z); sil = zz/(1.f+expf(-zz)); ov.z = f2bf(xv.z*r*nw.z*sil);
    zz = bf2f(zv.w); sil = zz/(1.f+expf(-zz)); ov.w = f2bf(xv.w*r*nw.w*sil);
    *(ushort4*)(og + row*128 + d0) = ov;
    row += 8;
  }
}

extern "C" void kernel_launch(void* const* d_in, const int* in_sizes, int n_in,
                              void* d_out, int out_size, void* d_ws, size_t ws_size,
                              hipStream_t stream){
  const float* hs    = (const float*)d_in[0];
  const float* Wqkv  = (const float*)d_in[1];
  const float* Wz    = (const float*)d_in[2];
  const float* Wb    = (const float*)d_in[3];
  const float* Wa    = (const float*)d_in[4];
  const float* convw = (const float*)d_in[5];
  const float* normw = (const float*)d_in[6];
  const float* Wout  = (const float*)d_in[7];
  const float* dtb   = (const float*)d_in[8];
  const float* alog  = (const float*)d_in[9];

  char* ws = (char*)d_ws;
  ushort* hsb   = (ushort*)(ws);                 // [0,16M)    hs bf16  -> later kn
  ushort* wqb   = (ushort*)(ws + (16l<<20));     // [16,48M)   Wqkv bf16 -> later v -> og
  ushort* wzb   = (ushort*)(ws + (48l<<20));     // [48,64M)   Wz bf16  -> later qn
  ushort* wob   = (ushort*)(ws + (64l<<20));     // [64,80M)   Wout bf16
  ushort* mixed = (ushort*)(ws + (80l<<20));     // [80,144M)  mixed bf16 -> later o_raw f32
  ushort* zb    = (ushort*)(ws + (144l<<20));    // [144,176M) z bf16
  float*  beta  = (float*)(ws + (176l<<20));     // 512K
  float*  cumLg = (float*)(ws + (176l<<20) + (512l<<10)); // 512K
  float*  glog  = (float*)(ws + (177l<<20));     // 512K
  ushort* Tg    = (ushort*)(ws + (178l<<20));    // [178,186M) T bf16 (also ba partials earlier)
  ushort* Mg    = (ushort*)(ws + (186l<<20));    // [186,194M) M bf16
  ushort* wbab  = (ushort*)(ws + (194l<<20));    // [194,194.5M) W_ba bf16 [128][2048]
  float*  bapr8 = (float*)(ws + (178l<<20));     // 8 x [4096][128] f32 = 16M, dead before chunk_prep
  ushort* kn = hsb;  ushort* qn = wzb;  ushort* vvp = wqb;  ushort* og = wqb;
  float*  o_raw = (float*)mixed;

  cvt_bf16<<<8192,  256, 0, stream>>>(hs,   hsb);
  cvt_bf16<<<16384, 256, 0, stream>>>(Wqkv, wqb);
  cvt_bf16<<<8192,  256, 0, stream>>>(Wz,   wzb);
  cvt_bf16<<<8192,  256, 0, stream>>>(Wout, wob);
  cvt_bf16<<<64,    256, 0, stream>>>(Wb,   wbab);          // rows 0..31
  cvt_bf16<<<64,    256, 0, stream>>>(Wa,   wbab + 65536);  // rows 32..63 (64..127 garbage, cols 64..127 of C unread)

  gemm256<1><<<512, 512, 0, stream>>>(hsb, wqb, (void*)mixed, 4096, 8192, 2048, 4, 16);
  gemm256<1><<<256, 512, 0, stream>>>(hsb, wzb, (void*)zb,    4096, 4096, 2048, 4, 8);
  gemm_ba<<<256, 256, 0, stream>>>(hsb, wbab, bapr8);
  ba_post2<<<1024, 256, 0, stream>>>(bapr8, dtb, alog, beta, glog);

  conv_qkv2<<<dim3(128,4), 256, 0, stream>>>(mixed, convw, qn, kn, vvp);
  chunk_prep<<<4096, 256, 0, stream>>>(qn, kn, beta, glog, Tg, Mg, cumLg);
  chunk_scan3<<<512, 256, 0, stream>>>(qn, kn, vvp, beta, cumLg, Tg, Mg, o_raw);
  norm_gate2<<<4096, 256, 0, stream>>>(o_raw, zb, normw, og);

  gemm256n128<0><<<256, 512, 0, stream>>>(og, wob, d_out, 4096, 2048, 4096, 4, 8);
}